// Round 1
// baseline (3347.905 us; speedup 1.0000x reference)
//
#include <hip/hip_runtime.h>

namespace {
constexpr int kB = 16;
constexpr int kN = 4096;
constexpr int kS = 1024;
constexpr int kK = 32;
constexpr int kCIN = 64;
constexpr int kCF = 67;   // 3 + 64
constexpr int kFD = 68;   // padded LDS row stride
constexpr int kSK = kS * kK;      // 32768
constexpr int kPT = kB * kSK;     // 524288
constexpr float kM = 524288.0f;   // BN count per channel
}

// ---------------------------------------------------------------- FPS ----
// One block per batch. Exact-arithmetic replica of the reference scan:
// emit current farthest, update dists with rn-ops, argmax (first-index tie).
__global__ __launch_bounds__(1024) void fps_kernel(const float* __restrict__ x,
                                                   float* __restrict__ new_xyz) {
  __shared__ float xs[kN], ys[kN], zs[kN];
  __shared__ float pv[2][16];
  __shared__ int   px[2][16];
  const int b = blockIdx.x;
  const int tid = threadIdx.x;
  const int lane = tid & 63;
  const int wid = tid >> 6;
  const float* xb = x + (size_t)b * kN * 3;
  for (int p = tid; p < kN; p += 1024) {
    xs[p] = xb[p * 3 + 0];
    ys[p] = xb[p * 3 + 1];
    zs[p] = xb[p * 3 + 2];
  }
  __syncthreads();
  float dmin[4] = {1e10f, 1e10f, 1e10f, 1e10f};
  int far = 0;
  for (int i = 0; i < kS; ++i) {
    if (tid < 3) {
      float v = (tid == 0) ? xs[far] : (tid == 1) ? ys[far] : zs[far];
      new_xyz[((size_t)b * kS + i) * 3 + tid] = v;
    }
    const float cx = xs[far], cy = ys[far], cz = zs[far];
    float bv = -1.0f;
    int bi = 0;
#pragma unroll
    for (int j = 0; j < 4; ++j) {
      const int p = tid + j * 1024;
      const float dx = __fsub_rn(xs[p], cx);
      const float dy = __fsub_rn(ys[p], cy);
      const float dz = __fsub_rn(zs[p], cz);
      const float t = __fadd_rn(__fadd_rn(__fmul_rn(dx, dx), __fmul_rn(dy, dy)),
                                __fmul_rn(dz, dz));
      dmin[j] = fminf(dmin[j], t);
      if (dmin[j] > bv) { bv = dmin[j]; bi = p; }  // ascending p: keeps first max
    }
#pragma unroll
    for (int off = 32; off > 0; off >>= 1) {
      const float ov = __shfl_down(bv, off, 64);
      const int oi = __shfl_down(bi, off, 64);
      if (ov > bv || (ov == bv && oi < bi)) { bv = ov; bi = oi; }
    }
    const int par = i & 1;
    if (lane == 0) { pv[par][wid] = bv; px[par][wid] = bi; }
    __syncthreads();
    float fv = (lane < 16) ? pv[par][lane] : -1.0f;
    int fi = (lane < 16) ? px[par][lane] : 0x7fffffff;
#pragma unroll
    for (int off = 8; off > 0; off >>= 1) {
      const float ov = __shfl_down(fv, off, 64);
      const int oi = __shfl_down(fi, off, 64);
      if (ov > fv || (ov == fv && oi < fi)) { fv = ov; fi = oi; }
    }
    far = __shfl(fi, 0, 64);
  }
}

// ---------------------------------------------------------- ball query ----
// One wave per centroid; ordered first-K within radius via ballot prefix.
__global__ __launch_bounds__(256) void ballq_kernel(const float* __restrict__ x,
                                                    const float* __restrict__ new_xyz,
                                                    int* __restrict__ idx) {
  const int g = blockIdx.x * 4 + (threadIdx.x >> 6);
  const int lane = threadIdx.x & 63;
  const int b = g >> 10;  // kS = 1024
  const float* xb = x + (size_t)b * kN * 3;
  const float nx = new_xyz[g * 3 + 0];
  const float ny = new_xyz[g * 3 + 1];
  const float nz = new_xyz[g * 3 + 2];
  const float RR = (float)(0.2 * 0.2);  // double product -> f32, matches JAX promotion
  int cnt = 0;
  int first = -1;
  for (int c = 0; c < kN / 64 && cnt < kK; ++c) {
    const int p = c * 64 + lane;
    const float dx = __fsub_rn(xb[p * 3 + 0], nx);
    const float dy = __fsub_rn(xb[p * 3 + 1], ny);
    const float dz = __fsub_rn(xb[p * 3 + 2], nz);
    const float t = __fadd_rn(__fadd_rn(__fmul_rn(dx, dx), __fmul_rn(dy, dy)),
                              __fmul_rn(dz, dz));
    const bool within = (t <= RR);
    const unsigned long long m = __ballot(within);
    if (first < 0 && m != 0ull) first = c * 64 + __builtin_ctzll(m);
    const int pos = cnt + (int)__popcll(m & ((1ull << lane) - 1ull));
    if (within && pos < kK) idx[(size_t)g * kK + pos] = p;
    cnt += (int)__popcll(m);
  }
  for (int k2 = cnt + lane; k2 < kK; k2 += 64) idx[(size_t)g * kK + k2] = first;
}

// ------------------------------------------------------------- helpers ----
__device__ __forceinline__ void load_bias4(float acc[4][4], const float* b, int tc) {
  const float4 bv = *(const float4*)(b + tc * 4);
  const float bb[4] = {bv.x, bv.y, bv.z, bv.w};
#pragma unroll
  for (int p2 = 0; p2 < 4; ++p2)
#pragma unroll
    for (int ci = 0; ci < 4; ++ci) acc[p2][ci] = bb[ci];
}

__device__ __forceinline__ void gemm4x4(const float* f_lds, const float* w_lds,
                                        int J, int tr, int tc, float acc[4][4]) {
  for (int j = 0; j < J; ++j) {
    const float4 w = *(const float4*)(w_lds + j * 64 + tc * 4);
#pragma unroll
    for (int p2 = 0; p2 < 4; ++p2) {
      const float fv = f_lds[(tr * 4 + p2) * kFD + j];
      acc[p2][0] = fmaf(fv, w.x, acc[p2][0]);
      acc[p2][1] = fmaf(fv, w.y, acc[p2][1]);
      acc[p2][2] = fmaf(fv, w.z, acc[p2][2]);
      acc[p2][3] = fmaf(fv, w.w, acc[p2][3]);
    }
  }
}

__device__ __forceinline__ void bnrelu4(float acc[4][4], const float* scp,
                                        const float* shp, int tc) {
  const float4 s4 = *(const float4*)(scp + tc * 4);
  const float4 h4 = *(const float4*)(shp + tc * 4);
  const float sv[4] = {s4.x, s4.y, s4.z, s4.w};
  const float hv[4] = {h4.x, h4.y, h4.z, h4.w};
#pragma unroll
  for (int p2 = 0; p2 < 4; ++p2)
#pragma unroll
    for (int ci = 0; ci < 4; ++ci)
      acc[p2][ci] = fmaxf(fmaf(acc[p2][ci], sv[ci], hv[ci]), 0.0f);
}

__device__ __forceinline__ void store_a4(const float acc[4][4], float* f_lds,
                                         int tr, int tc) {
#pragma unroll
  for (int p2 = 0; p2 < 4; ++p2)
#pragma unroll
    for (int ci = 0; ci < 4; ++ci)
      f_lds[(tr * 4 + p2) * kFD + tc * 4 + ci] = acc[p2][ci];
}

__device__ __forceinline__ void block_stats4(const float acc[4][4], float* red,
                                             int tc, int C) {
#pragma unroll
  for (int ci = 0; ci < 4; ++ci) {
    const int c = tc * 4 + ci;
    const float sv = acc[0][ci] + acc[1][ci] + acc[2][ci] + acc[3][ci];
    const float qv = acc[0][ci] * acc[0][ci] + acc[1][ci] * acc[1][ci] +
                     acc[2][ci] * acc[2][ci] + acc[3][ci] * acc[3][ci];
    atomicAdd(&red[c], sv);
    atomicAdd(&red[C + c], qv);
  }
}

// ---------------------------------------------------------- pass kernel ----
// STAGE 0: y0 stats. 1: y1 stats. 2: y2 stats. 3: full chain + K-maxpool.
// Block = 256 threads = 64 points (2 groups). f staged in LDS, W^T in LDS.
template <int STAGE>
__global__ __launch_bounds__(256) void pass_kernel(
    const float* __restrict__ x, const float* __restrict__ xc,
    const float* __restrict__ W0, const float* __restrict__ b0,
    const float* __restrict__ W1, const float* __restrict__ b1,
    const float* __restrict__ W2, const float* __restrict__ b2,
    const float* __restrict__ nxyz, const int* __restrict__ idx,
    const float* __restrict__ scsh, float* __restrict__ stats,
    float* __restrict__ out) {
  __shared__ float f_lds[64 * kFD];
  __shared__ float w_lds[64 * 128];
  __shared__ float red[256];
  const int tid = threadIdx.x;
  const int p0 = blockIdx.x * 64;
  red[tid] = 0.0f;

  {  // gather + stage f = [rel_xyz(3), feat(64)]
    const int th_p = tid >> 2;
    const int th_i = tid & 3;
    const int pg = p0 + th_p;
    const int b = pg >> 15;        // kSK = 32768
    const int r = pg & (kSK - 1);
    const int s = r >> 5;
    const int v = idx[pg];
    const float4* feat = (const float4*)(xc + ((size_t)b * kN + v) * kCIN) + th_i * 4;
    const float4 q0 = feat[0], q1 = feat[1], q2 = feat[2], q3 = feat[3];
    float* dst = f_lds + th_p * kFD + 3 + th_i * 16;
    dst[0] = q0.x; dst[1] = q0.y; dst[2] = q0.z; dst[3] = q0.w;
    dst[4] = q1.x; dst[5] = q1.y; dst[6] = q1.z; dst[7] = q1.w;
    dst[8] = q2.x; dst[9] = q2.y; dst[10] = q2.z; dst[11] = q2.w;
    dst[12] = q3.x; dst[13] = q3.y; dst[14] = q3.z; dst[15] = q3.w;
    if (th_i == 0) {
      const float* xp = x + ((size_t)b * kN + v) * 3;
      const float* np = nxyz + ((size_t)b * kS + s) * 3;
      float* fr = f_lds + th_p * kFD;
      fr[0] = __fsub_rn(xp[0], np[0]);
      fr[1] = __fsub_rn(xp[1], np[1]);
      fr[2] = __fsub_rn(xp[2], np[2]);
    }
  }
  for (int q = tid; q < 64 * kCF; q += 256) {  // W0^T
    const int c = q / kCF;
    const int j = q - c * kCF;
    w_lds[j * 64 + c] = W0[q];
  }
  __syncthreads();

  const int tc = tid & 15;
  const int tr = tid >> 4;

  float acc[4][4];
  load_bias4(acc, b0, tc);
  gemm4x4(f_lds, w_lds, kCF, tr, tc, acc);

  if constexpr (STAGE == 0) {
    block_stats4(acc, red, tc, 64);
    __syncthreads();
    if (tid < 128) atomicAdd(&stats[tid], red[tid]);
    return;
  } else {
    bnrelu4(acc, scsh + 0, scsh + 64, tc);
    __syncthreads();  // everyone done reading f_lds (f) and w_lds (W0)
    store_a4(acc, f_lds, tr, tc);
    for (int q = tid; q < 64 * 64; q += 256) {  // W1^T
      const int c = q >> 6, j = q & 63;
      w_lds[j * 64 + c] = W1[q];
    }
    __syncthreads();

    load_bias4(acc, b1, tc);
    gemm4x4(f_lds, w_lds, 64, tr, tc, acc);

    if constexpr (STAGE == 1) {
      block_stats4(acc, red, tc, 64);
      __syncthreads();
      if (tid < 128) atomicAdd(&stats[128 + tid], red[tid]);
      return;
    } else {
      bnrelu4(acc, scsh + 128, scsh + 192, tc);
      __syncthreads();
      store_a4(acc, f_lds, tr, tc);
      for (int q = tid; q < 128 * 64; q += 256) {  // W2^T (stride 128)
        const int c = q >> 6, j = q & 63;
        w_lds[j * 128 + c] = W2[q];
      }
      __syncthreads();

      const int c0 = tc * 8;
      float acc2[4][8];
      {
        const float4 ba = *(const float4*)(b2 + c0);
        const float4 bb = *(const float4*)(b2 + c0 + 4);
        const float bv[8] = {ba.x, ba.y, ba.z, ba.w, bb.x, bb.y, bb.z, bb.w};
#pragma unroll
        for (int p2 = 0; p2 < 4; ++p2)
#pragma unroll
          for (int ci = 0; ci < 8; ++ci) acc2[p2][ci] = bv[ci];
      }
      for (int j = 0; j < 64; ++j) {
        const float4 wa = *(const float4*)(w_lds + j * 128 + c0);
        const float4 wb = *(const float4*)(w_lds + j * 128 + c0 + 4);
#pragma unroll
        for (int p2 = 0; p2 < 4; ++p2) {
          const float fv = f_lds[(tr * 4 + p2) * kFD + j];
          acc2[p2][0] = fmaf(fv, wa.x, acc2[p2][0]);
          acc2[p2][1] = fmaf(fv, wa.y, acc2[p2][1]);
          acc2[p2][2] = fmaf(fv, wa.z, acc2[p2][2]);
          acc2[p2][3] = fmaf(fv, wa.w, acc2[p2][3]);
          acc2[p2][4] = fmaf(fv, wb.x, acc2[p2][4]);
          acc2[p2][5] = fmaf(fv, wb.y, acc2[p2][5]);
          acc2[p2][6] = fmaf(fv, wb.z, acc2[p2][6]);
          acc2[p2][7] = fmaf(fv, wb.w, acc2[p2][7]);
        }
      }

      if constexpr (STAGE == 2) {
#pragma unroll
        for (int ci = 0; ci < 8; ++ci) {
          const int c = c0 + ci;
          const float sv = acc2[0][ci] + acc2[1][ci] + acc2[2][ci] + acc2[3][ci];
          const float qv = acc2[0][ci] * acc2[0][ci] + acc2[1][ci] * acc2[1][ci] +
                           acc2[2][ci] * acc2[2][ci] + acc2[3][ci] * acc2[3][ci];
          atomicAdd(&red[c], sv);
          atomicAdd(&red[128 + c], qv);
        }
        __syncthreads();
        atomicAdd(&stats[256 + tid], red[tid]);
        return;
      } else {
        // STAGE == 3: bn2 + relu + max over K (relu>=0 so uint-max is valid)
        const float4 sa = *(const float4*)(scsh + 256 + c0);
        const float4 sb = *(const float4*)(scsh + 256 + c0 + 4);
        const float4 ha = *(const float4*)(scsh + 384 + c0);
        const float4 hb = *(const float4*)(scsh + 384 + c0 + 4);
        const float scv[8] = {sa.x, sa.y, sa.z, sa.w, sb.x, sb.y, sb.z, sb.w};
        const float shv[8] = {ha.x, ha.y, ha.z, ha.w, hb.x, hb.y, hb.z, hb.w};
        unsigned* redu = (unsigned*)red;
        const int grp = tr >> 3;  // 32-point groups: p = tr*4+pi -> group tr/8
#pragma unroll
        for (int ci = 0; ci < 8; ++ci) {
          const float m0 = fmaxf(fmaf(acc2[0][ci], scv[ci], shv[ci]), 0.0f);
          const float m1 = fmaxf(fmaf(acc2[1][ci], scv[ci], shv[ci]), 0.0f);
          const float m2 = fmaxf(fmaf(acc2[2][ci], scv[ci], shv[ci]), 0.0f);
          const float m3 = fmaxf(fmaf(acc2[3][ci], scv[ci], shv[ci]), 0.0f);
          const float mm = fmaxf(fmaxf(m0, m1), fmaxf(m2, m3));
          atomicMax(&redu[grp * 128 + c0 + ci], __float_as_uint(mm));
        }
        __syncthreads();
        const int sg = (p0 >> 5) + (tid >> 7);  // global group id
        const int ob = sg >> 10;
        const int os = sg & 1023;
        out[((size_t)ob * 128 + (tid & 127)) * kS + os] =
            __uint_as_float(((unsigned*)red)[tid]);
      }
    }
  }
}

// ------------------------------------------------------------ finalize ----
__global__ void finalize_kernel(const float* __restrict__ g, const float* __restrict__ be,
                                const float* __restrict__ st, float* __restrict__ sc,
                                float* __restrict__ sh, int C) {
  const int c = threadIdx.x;
  if (c < C) {
    const float mean = st[c] / kM;
    const float var = st[C + c] / kM - mean * mean;
    const float scale = g[c] / sqrtf(var + 1e-5f);
    sc[c] = scale;
    sh[c] = be[c] - mean * scale;
  }
}

// --------------------------------------------------------------- launch ----
extern "C" void kernel_launch(void* const* d_in, const int* in_sizes, int n_in,
                              void* d_out, int out_size, void* d_ws, size_t ws_size,
                              hipStream_t stream) {
  const float* x   = (const float*)d_in[0];
  const float* xc  = (const float*)d_in[1];
  const float* W0  = (const float*)d_in[2];
  const float* b0  = (const float*)d_in[3];
  const float* g0  = (const float*)d_in[4];
  const float* be0 = (const float*)d_in[5];
  const float* W1  = (const float*)d_in[6];
  const float* b1  = (const float*)d_in[7];
  const float* g1  = (const float*)d_in[8];
  const float* be1 = (const float*)d_in[9];
  const float* W2  = (const float*)d_in[10];
  const float* b2  = (const float*)d_in[11];
  const float* g2  = (const float*)d_in[12];
  const float* be2 = (const float*)d_in[13];
  float* out = (float*)d_out;
  char* ws = (char*)d_ws;
  float* nxyz  = (float*)(ws);              // 16*1024*3 f32 = 196608 B
  int*   idx   = (int*)(ws + 196608);       // 16*1024*32 i32 = 2097152 B
  float* stats = (float*)(ws + 2293760);    // 512 f32
  float* scsh  = (float*)(ws + 2295808);    // 512 f32
  (void)in_sizes; (void)n_in; (void)out_size; (void)ws_size;

  hipMemsetAsync(stats, 0, 512 * sizeof(float), stream);
  fps_kernel<<<16, 1024, 0, stream>>>(x, nxyz);
  ballq_kernel<<<(kB * kS) / 4, 256, 0, stream>>>(x, nxyz, idx);
  pass_kernel<0><<<kPT / 64, 256, 0, stream>>>(x, xc, W0, b0, W1, b1, W2, b2,
                                               nxyz, idx, scsh, stats, out);
  finalize_kernel<<<1, 128, 0, stream>>>(g0, be0, stats, scsh, scsh + 64, 64);
  pass_kernel<1><<<kPT / 64, 256, 0, stream>>>(x, xc, W0, b0, W1, b1, W2, b2,
                                               nxyz, idx, scsh, stats, out);
  finalize_kernel<<<1, 128, 0, stream>>>(g1, be1, stats + 128, scsh + 128, scsh + 192, 64);
  pass_kernel<2><<<kPT / 64, 256, 0, stream>>>(x, xc, W0, b0, W1, b1, W2, b2,
                                               nxyz, idx, scsh, stats, out);
  finalize_kernel<<<1, 128, 0, stream>>>(g2, be2, stats + 256, scsh + 256, scsh + 384, 128);
  pass_kernel<3><<<kPT / 64, 256, 0, stream>>>(x, xc, W0, b0, W1, b1, W2, b2,
                                               nxyz, idx, scsh, stats, out);
}

// Round 2
// 2448.116 us; speedup vs baseline: 1.3675x; 1.3675x over previous
//
#include <hip/hip_runtime.h>

namespace {
constexpr int kB = 16;
constexpr int kN = 4096;
constexpr int kS = 1024;
constexpr int kK = 32;
constexpr int kCIN = 64;
constexpr int kCF = 67;   // 3 + 64
constexpr int kFD = 68;   // padded LDS row stride
constexpr int kSK = kS * kK;      // 32768
constexpr int kPT = kB * kSK;     // 524288
constexpr float kM = 524288.0f;   // BN count per channel

constexpr size_t kOffIdx   = 196608;
constexpr size_t kOffStats = 2293760;
constexpr size_t kOffScsh  = 2295808;
constexpr size_t kOffY0    = 2297856;
constexpr size_t kSizeY    = (size_t)kPT * 64 * sizeof(float);  // 134217728
constexpr size_t kOffY1    = kOffY0 + kSizeY;
constexpr size_t kWsNeed   = kOffY1 + kSizeY;                   // ~258 MB
}

// ---------------------------------------------------------------- FPS ----
// One block (256 thr = 4 waves) per batch. Points + running dists live in
// registers (16 contiguous points per lane -> lane order == index order, so
// ballot/ctz preserves numpy first-occurrence argmax tie-break). Exact rn
// arithmetic matching the reference. One barrier per iteration.
__global__ __launch_bounds__(256) void fps_kernel(const float* __restrict__ x,
                                                  float* __restrict__ new_xyz) {
  __shared__ float xs[kN], ys[kN], zs[kN];
  __shared__ float pv[2][4];
  __shared__ int   pi[2][4];
  const int b = blockIdx.x;
  const int tid = threadIdx.x;
  const int lane = tid & 63;
  const int wid = tid >> 6;
  const float* xb = x + (size_t)b * kN * 3;
  for (int q = tid; q < kN; q += 256) {
    xs[q] = xb[q * 3 + 0];
    ys[q] = xb[q * 3 + 1];
    zs[q] = xb[q * 3 + 2];
  }
  __syncthreads();
  float px[16], py[16], pz[16], dm[16];
#pragma unroll
  for (int j = 0; j < 16; ++j) {
    const int p = tid * 16 + j;
    px[j] = xs[p]; py[j] = ys[p]; pz[j] = zs[p];
    dm[j] = 1e10f;
  }
  int far = 0;
  for (int i = 0; i < kS; ++i) {
    const float cx = xs[far], cy = ys[far], cz = zs[far];
    if (tid == 0) {
      float* o = new_xyz + ((size_t)b * kS + i) * 3;
      o[0] = cx; o[1] = cy; o[2] = cz;
    }
    float bv = -1.0f;
    int bj = 0;
#pragma unroll
    for (int j = 0; j < 16; ++j) {
      const float dx = __fsub_rn(px[j], cx);
      const float dy = __fsub_rn(py[j], cy);
      const float dz = __fsub_rn(pz[j], cz);
      const float t = __fadd_rn(__fadd_rn(__fmul_rn(dx, dx), __fmul_rn(dy, dy)),
                                __fmul_rn(dz, dz));
      dm[j] = fminf(dm[j], t);
      if (dm[j] > bv) { bv = dm[j]; bj = j; }  // ascending j: first max kept
    }
    const float lb = bv;
    float wv = bv;
#pragma unroll
    for (int k = 1; k < 64; k <<= 1) wv = fmaxf(wv, __shfl_xor(wv, k, 64));
    const unsigned long long m = __ballot(lb == wv);
    const int src = (int)__builtin_ctzll(m);
    const int par = i & 1;
    if (lane == src) { pv[par][wid] = wv; pi[par][wid] = tid * 16 + bj; }
    __syncthreads();
    float fv = pv[par][0];
    int fi = pi[par][0];
#pragma unroll
    for (int w = 1; w < 4; ++w) {
      const float v2 = pv[par][w];
      const int i2 = pi[par][w];
      if (v2 > fv) { fv = v2; fi = i2; }  // ascending wave: first max kept
    }
    far = fi;
  }
}

// ---------------------------------------------------------- ball query ----
__global__ __launch_bounds__(256) void ballq_kernel(const float* __restrict__ x,
                                                    const float* __restrict__ new_xyz,
                                                    int* __restrict__ idx) {
  const int g = blockIdx.x * 4 + (threadIdx.x >> 6);
  const int lane = threadIdx.x & 63;
  const int b = g >> 10;  // kS = 1024
  const float* xb = x + (size_t)b * kN * 3;
  const float nx = new_xyz[g * 3 + 0];
  const float ny = new_xyz[g * 3 + 1];
  const float nz = new_xyz[g * 3 + 2];
  const float RR = (float)(0.2 * 0.2);
  int cnt = 0;
  int first = -1;
  for (int c = 0; c < kN / 64 && cnt < kK; ++c) {
    const int p = c * 64 + lane;
    const float dx = __fsub_rn(xb[p * 3 + 0], nx);
    const float dy = __fsub_rn(xb[p * 3 + 1], ny);
    const float dz = __fsub_rn(xb[p * 3 + 2], nz);
    const float t = __fadd_rn(__fadd_rn(__fmul_rn(dx, dx), __fmul_rn(dy, dy)),
                              __fmul_rn(dz, dz));
    const bool within = (t <= RR);
    const unsigned long long m = __ballot(within);
    if (first < 0 && m != 0ull) first = c * 64 + __builtin_ctzll(m);
    const int pos = cnt + (int)__popcll(m & ((1ull << lane) - 1ull));
    if (within && pos < kK) idx[(size_t)g * kK + pos] = p;
    cnt += (int)__popcll(m);
  }
  for (int k2 = cnt + lane; k2 < kK; k2 += 64) idx[(size_t)g * kK + k2] = first;
}

// ------------------------------------------------------------- helpers ----
__device__ __forceinline__ void load_bias4(float acc[4][4], const float* b, int tc) {
  const float4 bv = *(const float4*)(b + tc * 4);
  const float bb[4] = {bv.x, bv.y, bv.z, bv.w};
#pragma unroll
  for (int p2 = 0; p2 < 4; ++p2)
#pragma unroll
    for (int ci = 0; ci < 4; ++ci) acc[p2][ci] = bb[ci];
}

__device__ __forceinline__ void gemm4x4(const float* f_lds, const float* w_lds,
                                        int J, int tr, int tc, float acc[4][4]) {
  for (int j = 0; j < J; ++j) {
    const float4 w = *(const float4*)(w_lds + j * 64 + tc * 4);
#pragma unroll
    for (int p2 = 0; p2 < 4; ++p2) {
      const float fv = f_lds[(tr * 4 + p2) * kFD + j];
      acc[p2][0] = fmaf(fv, w.x, acc[p2][0]);
      acc[p2][1] = fmaf(fv, w.y, acc[p2][1]);
      acc[p2][2] = fmaf(fv, w.z, acc[p2][2]);
      acc[p2][3] = fmaf(fv, w.w, acc[p2][3]);
    }
  }
}

__device__ __forceinline__ void bnrelu4(float acc[4][4], const float* scp,
                                        const float* shp, int tc) {
  const float4 s4 = *(const float4*)(scp + tc * 4);
  const float4 h4 = *(const float4*)(shp + tc * 4);
  const float sv[4] = {s4.x, s4.y, s4.z, s4.w};
  const float hv[4] = {h4.x, h4.y, h4.z, h4.w};
#pragma unroll
  for (int p2 = 0; p2 < 4; ++p2)
#pragma unroll
    for (int ci = 0; ci < 4; ++ci)
      acc[p2][ci] = fmaxf(fmaf(acc[p2][ci], sv[ci], hv[ci]), 0.0f);
}

__device__ __forceinline__ void store_a4(const float acc[4][4], float* f_lds,
                                         int tr, int tc) {
#pragma unroll
  for (int p2 = 0; p2 < 4; ++p2)
#pragma unroll
    for (int ci = 0; ci < 4; ++ci)
      f_lds[(tr * 4 + p2) * kFD + tc * 4 + ci] = acc[p2][ci];
}

__device__ __forceinline__ void block_stats4(const float acc[4][4], float* red,
                                             int tc, int C) {
#pragma unroll
  for (int ci = 0; ci < 4; ++ci) {
    const int c = tc * 4 + ci;
    const float sv = acc[0][ci] + acc[1][ci] + acc[2][ci] + acc[3][ci];
    const float qv = acc[0][ci] * acc[0][ci] + acc[1][ci] * acc[1][ci] +
                     acc[2][ci] * acc[2][ci] + acc[3][ci] * acc[3][ci];
    atomicAdd(&red[c], sv);
    atomicAdd(&red[C + c], qv);
  }
}

// gather f = [rel_xyz(3), feat(64)] for 64 points into f_lds
__device__ __forceinline__ void gather_f(const float* __restrict__ x,
                                         const float* __restrict__ xc,
                                         const float* __restrict__ nxyz,
                                         const int* __restrict__ idx,
                                         float* f_lds, int p0, int tid) {
  const int th_p = tid >> 2;
  const int th_i = tid & 3;
  const int pg = p0 + th_p;
  const int b = pg >> 15;        // kSK = 32768
  const int r = pg & (kSK - 1);
  const int s = r >> 5;
  const int v = idx[pg];
  const float4* feat = (const float4*)(xc + ((size_t)b * kN + v) * kCIN) + th_i * 4;
  const float4 q0 = feat[0], q1 = feat[1], q2 = feat[2], q3 = feat[3];
  float* dst = f_lds + th_p * kFD + 3 + th_i * 16;
  dst[0] = q0.x; dst[1] = q0.y; dst[2] = q0.z; dst[3] = q0.w;
  dst[4] = q1.x; dst[5] = q1.y; dst[6] = q1.z; dst[7] = q1.w;
  dst[8] = q2.x; dst[9] = q2.y; dst[10] = q2.z; dst[11] = q2.w;
  dst[12] = q3.x; dst[13] = q3.y; dst[14] = q3.z; dst[15] = q3.w;
  if (th_i == 0) {
    const float* xp = x + ((size_t)b * kN + v) * 3;
    const float* np = nxyz + ((size_t)b * kS + s) * 3;
    float* fr = f_lds + th_p * kFD;
    fr[0] = __fsub_rn(xp[0], np[0]);
    fr[1] = __fsub_rn(xp[1], np[1]);
    fr[2] = __fsub_rn(xp[2], np[2]);
  }
}

// =================== STORAGE PATH (large ws) ===============================
// pass1: gather -> GEMM0 -> stats0 + store y0 (pre-BN)
__global__ __launch_bounds__(256) void pass1s_kernel(
    const float* __restrict__ x, const float* __restrict__ xc,
    const float* __restrict__ W0, const float* __restrict__ b0,
    const float* __restrict__ nxyz, const int* __restrict__ idx,
    float* __restrict__ stats, float* __restrict__ y0) {
  __shared__ float f_lds[64 * kFD];
  __shared__ float w_lds[kCF * 64];
  __shared__ float red[256];
  const int tid = threadIdx.x;
  const int p0 = blockIdx.x * 64;
  red[tid] = 0.0f;
  gather_f(x, xc, nxyz, idx, f_lds, p0, tid);
  for (int q = tid; q < 64 * kCF; q += 256) {
    const int c = q / kCF;
    const int j = q - c * kCF;
    w_lds[j * 64 + c] = W0[q];
  }
  __syncthreads();
  const int tc = tid & 15;
  const int tr = tid >> 4;
  float acc[4][4];
  load_bias4(acc, b0, tc);
  gemm4x4(f_lds, w_lds, kCF, tr, tc, acc);
#pragma unroll
  for (int p2 = 0; p2 < 4; ++p2)
    *(float4*)(y0 + ((size_t)(p0 + tr * 4 + p2)) * 64 + tc * 4) =
        make_float4(acc[p2][0], acc[p2][1], acc[p2][2], acc[p2][3]);
  block_stats4(acc, red, tc, 64);
  __syncthreads();
  if (tid < 128) atomicAdd(&stats[tid], red[tid]);
}

// pass2: load y0 -> bnrelu0 -> GEMM1 -> stats1 + store y1 (pre-BN)
__global__ __launch_bounds__(256) void pass2s_kernel(
    const float* __restrict__ y0, const float* __restrict__ W1,
    const float* __restrict__ b1, const float* __restrict__ scsh,
    float* __restrict__ stats, float* __restrict__ y1) {
  __shared__ float f_lds[64 * kFD];
  __shared__ float w_lds[64 * 64];
  __shared__ float red[256];
  const int tid = threadIdx.x;
  const int p0 = blockIdx.x * 64;
  red[tid] = 0.0f;
  const int tc = tid & 15;
  const int tr = tid >> 4;
  float acc[4][4];
#pragma unroll
  for (int p2 = 0; p2 < 4; ++p2) {
    const float4 v = *(const float4*)(y0 + ((size_t)(p0 + tr * 4 + p2)) * 64 + tc * 4);
    acc[p2][0] = v.x; acc[p2][1] = v.y; acc[p2][2] = v.z; acc[p2][3] = v.w;
  }
  bnrelu4(acc, scsh + 0, scsh + 64, tc);
  store_a4(acc, f_lds, tr, tc);
  for (int q = tid; q < 64 * 64; q += 256) {
    const int c = q >> 6, j = q & 63;
    w_lds[j * 64 + c] = W1[q];
  }
  __syncthreads();
  load_bias4(acc, b1, tc);
  gemm4x4(f_lds, w_lds, 64, tr, tc, acc);
#pragma unroll
  for (int p2 = 0; p2 < 4; ++p2)
    *(float4*)(y1 + ((size_t)(p0 + tr * 4 + p2)) * 64 + tc * 4) =
        make_float4(acc[p2][0], acc[p2][1], acc[p2][2], acc[p2][3]);
  block_stats4(acc, red, tc, 64);
  __syncthreads();
  if (tid < 128) atomicAdd(&stats[128 + tid], red[tid]);
}

// pass3/4: load y1 -> bnrelu1 -> GEMM2 -> {stats2 | bn2relu+maxpool}
template <bool FINAL>
__global__ __launch_bounds__(256) void pass34s_kernel(
    const float* __restrict__ y1, const float* __restrict__ W2,
    const float* __restrict__ b2, const float* __restrict__ scsh,
    float* __restrict__ stats, float* __restrict__ out) {
  __shared__ float f_lds[64 * kFD];
  __shared__ float w_lds[64 * 128];
  __shared__ float red[256];
  const int tid = threadIdx.x;
  const int p0 = blockIdx.x * 64;
  red[tid] = 0.0f;
  const int tc = tid & 15;
  const int tr = tid >> 4;
  float acc[4][4];
#pragma unroll
  for (int p2 = 0; p2 < 4; ++p2) {
    const float4 v = *(const float4*)(y1 + ((size_t)(p0 + tr * 4 + p2)) * 64 + tc * 4);
    acc[p2][0] = v.x; acc[p2][1] = v.y; acc[p2][2] = v.z; acc[p2][3] = v.w;
  }
  bnrelu4(acc, scsh + 128, scsh + 192, tc);
  store_a4(acc, f_lds, tr, tc);
  for (int q = tid; q < 128 * 64; q += 256) {
    const int c = q >> 6, j = q & 63;
    w_lds[j * 128 + c] = W2[q];
  }
  __syncthreads();

  const int c0 = tc * 8;
  float acc2[4][8];
  {
    const float4 ba = *(const float4*)(b2 + c0);
    const float4 bb = *(const float4*)(b2 + c0 + 4);
    const float bv[8] = {ba.x, ba.y, ba.z, ba.w, bb.x, bb.y, bb.z, bb.w};
#pragma unroll
    for (int p2 = 0; p2 < 4; ++p2)
#pragma unroll
      for (int ci = 0; ci < 8; ++ci) acc2[p2][ci] = bv[ci];
  }
  for (int j = 0; j < 64; ++j) {
    const float4 wa = *(const float4*)(w_lds + j * 128 + c0);
    const float4 wb = *(const float4*)(w_lds + j * 128 + c0 + 4);
#pragma unroll
    for (int p2 = 0; p2 < 4; ++p2) {
      const float fv = f_lds[(tr * 4 + p2) * kFD + j];
      acc2[p2][0] = fmaf(fv, wa.x, acc2[p2][0]);
      acc2[p2][1] = fmaf(fv, wa.y, acc2[p2][1]);
      acc2[p2][2] = fmaf(fv, wa.z, acc2[p2][2]);
      acc2[p2][3] = fmaf(fv, wa.w, acc2[p2][3]);
      acc2[p2][4] = fmaf(fv, wb.x, acc2[p2][4]);
      acc2[p2][5] = fmaf(fv, wb.y, acc2[p2][5]);
      acc2[p2][6] = fmaf(fv, wb.z, acc2[p2][6]);
      acc2[p2][7] = fmaf(fv, wb.w, acc2[p2][7]);
    }
  }

  if constexpr (!FINAL) {
#pragma unroll
    for (int ci = 0; ci < 8; ++ci) {
      const int c = c0 + ci;
      const float sv = acc2[0][ci] + acc2[1][ci] + acc2[2][ci] + acc2[3][ci];
      const float qv = acc2[0][ci] * acc2[0][ci] + acc2[1][ci] * acc2[1][ci] +
                       acc2[2][ci] * acc2[2][ci] + acc2[3][ci] * acc2[3][ci];
      atomicAdd(&red[c], sv);
      atomicAdd(&red[128 + c], qv);
    }
    __syncthreads();
    atomicAdd(&stats[256 + tid], red[tid]);
  } else {
    const float4 sa = *(const float4*)(scsh + 256 + c0);
    const float4 sb = *(const float4*)(scsh + 256 + c0 + 4);
    const float4 ha = *(const float4*)(scsh + 384 + c0);
    const float4 hb = *(const float4*)(scsh + 384 + c0 + 4);
    const float scv[8] = {sa.x, sa.y, sa.z, sa.w, sb.x, sb.y, sb.z, sb.w};
    const float shv[8] = {ha.x, ha.y, ha.z, ha.w, hb.x, hb.y, hb.z, hb.w};
    unsigned* redu = (unsigned*)red;
    const int grp = tr >> 3;
#pragma unroll
    for (int ci = 0; ci < 8; ++ci) {
      const float m0 = fmaxf(fmaf(acc2[0][ci], scv[ci], shv[ci]), 0.0f);
      const float m1 = fmaxf(fmaf(acc2[1][ci], scv[ci], shv[ci]), 0.0f);
      const float m2 = fmaxf(fmaf(acc2[2][ci], scv[ci], shv[ci]), 0.0f);
      const float m3 = fmaxf(fmaf(acc2[3][ci], scv[ci], shv[ci]), 0.0f);
      const float mm = fmaxf(fmaxf(m0, m1), fmaxf(m2, m3));
      atomicMax(&redu[grp * 128 + c0 + ci], __float_as_uint(mm));
    }
    __syncthreads();
    const int sg = (p0 >> 5) + (tid >> 7);
    const int ob = sg >> 10;
    const int os = sg & 1023;
    out[((size_t)ob * 128 + (tid & 127)) * kS + os] =
        __uint_as_float(((unsigned*)red)[tid]);
  }
}

// =================== RECOMPUTE PATH (small ws fallback) ====================
template <int STAGE>
__global__ __launch_bounds__(256) void pass_kernel(
    const float* __restrict__ x, const float* __restrict__ xc,
    const float* __restrict__ W0, const float* __restrict__ b0,
    const float* __restrict__ W1, const float* __restrict__ b1,
    const float* __restrict__ W2, const float* __restrict__ b2,
    const float* __restrict__ nxyz, const int* __restrict__ idx,
    const float* __restrict__ scsh, float* __restrict__ stats,
    float* __restrict__ out) {
  __shared__ float f_lds[64 * kFD];
  __shared__ float w_lds[64 * 128];
  __shared__ float red[256];
  const int tid = threadIdx.x;
  const int p0 = blockIdx.x * 64;
  red[tid] = 0.0f;
  gather_f(x, xc, nxyz, idx, f_lds, p0, tid);
  for (int q = tid; q < 64 * kCF; q += 256) {
    const int c = q / kCF;
    const int j = q - c * kCF;
    w_lds[j * 64 + c] = W0[q];
  }
  __syncthreads();

  const int tc = tid & 15;
  const int tr = tid >> 4;

  float acc[4][4];
  load_bias4(acc, b0, tc);
  gemm4x4(f_lds, w_lds, kCF, tr, tc, acc);

  if constexpr (STAGE == 0) {
    block_stats4(acc, red, tc, 64);
    __syncthreads();
    if (tid < 128) atomicAdd(&stats[tid], red[tid]);
    return;
  } else {
    bnrelu4(acc, scsh + 0, scsh + 64, tc);
    __syncthreads();
    store_a4(acc, f_lds, tr, tc);
    for (int q = tid; q < 64 * 64; q += 256) {
      const int c = q >> 6, j = q & 63;
      w_lds[j * 64 + c] = W1[q];
    }
    __syncthreads();

    load_bias4(acc, b1, tc);
    gemm4x4(f_lds, w_lds, 64, tr, tc, acc);

    if constexpr (STAGE == 1) {
      block_stats4(acc, red, tc, 64);
      __syncthreads();
      if (tid < 128) atomicAdd(&stats[128 + tid], red[tid]);
      return;
    } else {
      bnrelu4(acc, scsh + 128, scsh + 192, tc);
      __syncthreads();
      store_a4(acc, f_lds, tr, tc);
      for (int q = tid; q < 128 * 64; q += 256) {
        const int c = q >> 6, j = q & 63;
        w_lds[j * 128 + c] = W2[q];
      }
      __syncthreads();

      const int c0 = tc * 8;
      float acc2[4][8];
      {
        const float4 ba = *(const float4*)(b2 + c0);
        const float4 bb = *(const float4*)(b2 + c0 + 4);
        const float bv[8] = {ba.x, ba.y, ba.z, ba.w, bb.x, bb.y, bb.z, bb.w};
#pragma unroll
        for (int p2 = 0; p2 < 4; ++p2)
#pragma unroll
          for (int ci = 0; ci < 8; ++ci) acc2[p2][ci] = bv[ci];
      }
      for (int j = 0; j < 64; ++j) {
        const float4 wa = *(const float4*)(w_lds + j * 128 + c0);
        const float4 wb = *(const float4*)(w_lds + j * 128 + c0 + 4);
#pragma unroll
        for (int p2 = 0; p2 < 4; ++p2) {
          const float fv = f_lds[(tr * 4 + p2) * kFD + j];
          acc2[p2][0] = fmaf(fv, wa.x, acc2[p2][0]);
          acc2[p2][1] = fmaf(fv, wa.y, acc2[p2][1]);
          acc2[p2][2] = fmaf(fv, wa.z, acc2[p2][2]);
          acc2[p2][3] = fmaf(fv, wa.w, acc2[p2][3]);
          acc2[p2][4] = fmaf(fv, wb.x, acc2[p2][4]);
          acc2[p2][5] = fmaf(fv, wb.y, acc2[p2][5]);
          acc2[p2][6] = fmaf(fv, wb.z, acc2[p2][6]);
          acc2[p2][7] = fmaf(fv, wb.w, acc2[p2][7]);
        }
      }

      if constexpr (STAGE == 2) {
#pragma unroll
        for (int ci = 0; ci < 8; ++ci) {
          const int c = c0 + ci;
          const float sv = acc2[0][ci] + acc2[1][ci] + acc2[2][ci] + acc2[3][ci];
          const float qv = acc2[0][ci] * acc2[0][ci] + acc2[1][ci] * acc2[1][ci] +
                           acc2[2][ci] * acc2[2][ci] + acc2[3][ci] * acc2[3][ci];
          atomicAdd(&red[c], sv);
          atomicAdd(&red[128 + c], qv);
        }
        __syncthreads();
        atomicAdd(&stats[256 + tid], red[tid]);
        return;
      } else {
        const float4 sa = *(const float4*)(scsh + 256 + c0);
        const float4 sb = *(const float4*)(scsh + 256 + c0 + 4);
        const float4 ha = *(const float4*)(scsh + 384 + c0);
        const float4 hb = *(const float4*)(scsh + 384 + c0 + 4);
        const float scv[8] = {sa.x, sa.y, sa.z, sa.w, sb.x, sb.y, sb.z, sb.w};
        const float shv[8] = {ha.x, ha.y, ha.z, ha.w, hb.x, hb.y, hb.z, hb.w};
        unsigned* redu = (unsigned*)red;
        const int grp = tr >> 3;
#pragma unroll
        for (int ci = 0; ci < 8; ++ci) {
          const float m0 = fmaxf(fmaf(acc2[0][ci], scv[ci], shv[ci]), 0.0f);
          const float m1 = fmaxf(fmaf(acc2[1][ci], scv[ci], shv[ci]), 0.0f);
          const float m2 = fmaxf(fmaf(acc2[2][ci], scv[ci], shv[ci]), 0.0f);
          const float m3 = fmaxf(fmaf(acc2[3][ci], scv[ci], shv[ci]), 0.0f);
          const float mm = fmaxf(fmaxf(m0, m1), fmaxf(m2, m3));
          atomicMax(&redu[grp * 128 + c0 + ci], __float_as_uint(mm));
        }
        __syncthreads();
        const int sg = (p0 >> 5) + (tid >> 7);
        const int ob = sg >> 10;
        const int os = sg & 1023;
        out[((size_t)ob * 128 + (tid & 127)) * kS + os] =
            __uint_as_float(((unsigned*)red)[tid]);
      }
    }
  }
}

// ------------------------------------------------------------ finalize ----
__global__ void finalize_kernel(const float* __restrict__ g, const float* __restrict__ be,
                                const float* __restrict__ st, float* __restrict__ sc,
                                float* __restrict__ sh, int C) {
  const int c = threadIdx.x;
  if (c < C) {
    const float mean = st[c] / kM;
    const float var = st[C + c] / kM - mean * mean;
    const float scale = g[c] / sqrtf(var + 1e-5f);
    sc[c] = scale;
    sh[c] = be[c] - mean * scale;
  }
}

// --------------------------------------------------------------- launch ----
extern "C" void kernel_launch(void* const* d_in, const int* in_sizes, int n_in,
                              void* d_out, int out_size, void* d_ws, size_t ws_size,
                              hipStream_t stream) {
  const float* x   = (const float*)d_in[0];
  const float* xc  = (const float*)d_in[1];
  const float* W0  = (const float*)d_in[2];
  const float* b0  = (const float*)d_in[3];
  const float* g0  = (const float*)d_in[4];
  const float* be0 = (const float*)d_in[5];
  const float* W1  = (const float*)d_in[6];
  const float* b1  = (const float*)d_in[7];
  const float* g1  = (const float*)d_in[8];
  const float* be1 = (const float*)d_in[9];
  const float* W2  = (const float*)d_in[10];
  const float* b2  = (const float*)d_in[11];
  const float* g2  = (const float*)d_in[12];
  const float* be2 = (const float*)d_in[13];
  float* out = (float*)d_out;
  char* ws = (char*)d_ws;
  float* nxyz  = (float*)(ws);
  int*   idx   = (int*)(ws + kOffIdx);
  float* stats = (float*)(ws + kOffStats);
  float* scsh  = (float*)(ws + kOffScsh);
  float* y0    = (float*)(ws + kOffY0);
  float* y1    = (float*)(ws + kOffY1);
  (void)in_sizes; (void)n_in; (void)out_size;

  hipMemsetAsync(stats, 0, 512 * sizeof(float), stream);
  fps_kernel<<<kB, 256, 0, stream>>>(x, nxyz);
  ballq_kernel<<<(kB * kS) / 4, 256, 0, stream>>>(x, nxyz, idx);

  if (ws_size >= kWsNeed) {
    pass1s_kernel<<<kPT / 64, 256, 0, stream>>>(x, xc, W0, b0, nxyz, idx, stats, y0);
    finalize_kernel<<<1, 128, 0, stream>>>(g0, be0, stats, scsh, scsh + 64, 64);
    pass2s_kernel<<<kPT / 64, 256, 0, stream>>>(y0, W1, b1, scsh, stats, y1);
    finalize_kernel<<<1, 128, 0, stream>>>(g1, be1, stats + 128, scsh + 128, scsh + 192, 64);
    pass34s_kernel<false><<<kPT / 64, 256, 0, stream>>>(y1, W2, b2, scsh, stats, out);
    finalize_kernel<<<1, 128, 0, stream>>>(g2, be2, stats + 256, scsh + 256, scsh + 384, 128);
    pass34s_kernel<true><<<kPT / 64, 256, 0, stream>>>(y1, W2, b2, scsh, stats, out);
  } else {
    pass_kernel<0><<<kPT / 64, 256, 0, stream>>>(x, xc, W0, b0, W1, b1, W2, b2,
                                                 nxyz, idx, scsh, stats, out);
    finalize_kernel<<<1, 128, 0, stream>>>(g0, be0, stats, scsh, scsh + 64, 64);
    pass_kernel<1><<<kPT / 64, 256, 0, stream>>>(x, xc, W0, b0, W1, b1, W2, b2,
                                                 nxyz, idx, scsh, stats, out);
    finalize_kernel<<<1, 128, 0, stream>>>(g1, be1, stats + 128, scsh + 128, scsh + 192, 64);
    pass_kernel<2><<<kPT / 64, 256, 0, stream>>>(x, xc, W0, b0, W1, b1, W2, b2,
                                                 nxyz, idx, scsh, stats, out);
    finalize_kernel<<<1, 128, 0, stream>>>(g2, be2, stats + 256, scsh + 256, scsh + 384, 128);
    pass_kernel<3><<<kPT / 64, 256, 0, stream>>>(x, xc, W0, b0, W1, b1, W2, b2,
                                                 nxyz, idx, scsh, stats, out);
  }
}

// Round 5
// 1313.877 us; speedup vs baseline: 2.5481x; 1.8633x over previous
//
#include <hip/hip_runtime.h>

namespace {
constexpr int kB = 16;
constexpr int kN = 4096;
constexpr int kS = 1024;
constexpr int kK = 32;
constexpr int kCIN = 64;
constexpr int kCF = 67;   // 3 + 64
constexpr int kFD = 68;   // padded LDS row stride (old fallback path)
constexpr int kSK = kS * kK;      // 32768
constexpr int kPT = kB * kSK;     // 524288
constexpr float kM = 524288.0f;   // BN count per channel

constexpr size_t kOffIdx   = 196608;
constexpr size_t kOffStats = 2293760;
constexpr size_t kOffScsh  = 2295808;
constexpr size_t kOffU     = 2297856;
constexpr size_t kWsNeedU  = kOffU + (size_t)kB * kN * 64 * sizeof(float);  // 19075072

constexpr int kLdsK = 72;  // bf16 row stride: 144 B = 9*16 (16B-aligned, 2-way banks)

using bf16x8 = __attribute__((ext_vector_type(8))) short;
using f32x4  = __attribute__((ext_vector_type(4))) float;
}

__device__ __forceinline__ unsigned short f2bf(float f) {
  unsigned u = __float_as_uint(f);
  u += 0x7fffu + ((u >> 16) & 1u);
  return (unsigned short)(u >> 16);
}
__device__ __forceinline__ unsigned pack2bf(float a, float b) {
  return (unsigned)f2bf(a) | ((unsigned)f2bf(b) << 16);
}

// ---------------------------------------------------------------- FPS ----
// 4 waves, 16 pts/lane in registers. Per iter: rn-exact dist update, fmax
// tree, 6x shfl_xor wave max, ballot+ctz winner (lane order == index order
// -> first-occurrence tie-break preserved), eq-mask for in-lane index.
__device__ void fps_body(const float* __restrict__ x, float* __restrict__ new_xyz,
                         int b, int tid, char* smem) {
  float* xs = (float*)smem;
  float* ys = xs + kN;
  float* zs = ys + kN;
  float* pv = zs + kN;           // [2][4]
  int*   pi = (int*)(pv + 8);    // [2][4]
  const int lane = tid & 63;
  const int wid = tid >> 6;
  const float* xb = x + (size_t)b * kN * 3;
  for (int q = tid; q < kN; q += 256) {
    xs[q] = xb[q * 3 + 0];
    ys[q] = xb[q * 3 + 1];
    zs[q] = xb[q * 3 + 2];
  }
  __syncthreads();
  float px[16], py[16], pz[16], dm[16];
#pragma unroll
  for (int j = 0; j < 16; ++j) {
    const int p = tid * 16 + j;
    px[j] = xs[p]; py[j] = ys[p]; pz[j] = zs[p];
    dm[j] = 1e10f;
  }
  int far = 0;
  for (int i = 0; i < kS; ++i) {
    const float cx = xs[far], cy = ys[far], cz = zs[far];
    if (tid == 0) {
      float* o = new_xyz + ((size_t)b * kS + i) * 3;
      o[0] = cx; o[1] = cy; o[2] = cz;
    }
#pragma unroll
    for (int j = 0; j < 16; ++j) {
      const float dx = __fsub_rn(px[j], cx);
      const float dy = __fsub_rn(py[j], cy);
      const float dz = __fsub_rn(pz[j], cz);
      const float t = __fadd_rn(__fadd_rn(__fmul_rn(dx, dx), __fmul_rn(dy, dy)),
                                __fmul_rn(dz, dz));
      dm[j] = fminf(dm[j], t);
    }
    float t8[8], t4[4], t2[2];
#pragma unroll
    for (int j = 0; j < 8; ++j) t8[j] = fmaxf(dm[j], dm[j + 8]);
#pragma unroll
    for (int j = 0; j < 4; ++j) t4[j] = fmaxf(t8[j], t8[j + 4]);
#pragma unroll
    for (int j = 0; j < 2; ++j) t2[j] = fmaxf(t4[j], t4[j + 2]);
    const float bv = fmaxf(t2[0], t2[1]);
    float wv = bv;
#pragma unroll
    for (int k = 1; k < 64; k <<= 1) wv = fmaxf(wv, __shfl_xor(wv, k, 64));
    unsigned msk = 0;
#pragma unroll
    for (int j = 0; j < 16; ++j) msk |= (dm[j] == bv ? 1u : 0u) << j;
    const unsigned long long bal = __ballot(bv == wv);
    const int win = (int)__builtin_ctzll(bal);
    const unsigned wmsk = (unsigned)__shfl((int)msk, win, 64);
    const int wfar = (wid * 64 + win) * 16 + (int)__builtin_ctz(wmsk);
    const int par = i & 1;
    if (lane == 0) { pv[par * 4 + wid] = wv; pi[par * 4 + wid] = wfar; }
    __syncthreads();
    float fv = pv[par * 4 + 0];
    int fi = pi[par * 4 + 0];
#pragma unroll
    for (int w = 1; w < 4; ++w) {
      const float v2 = pv[par * 4 + w];
      const int i2 = pi[par * 4 + w];
      if (v2 > fv) { fv = v2; fi = i2; }  // ascending wave: first-occurrence
    }
    far = fi;
  }
}

// --------------------------------------------- U = feat . W0[:,3:]^T ----
// Unique-point GEMM: 65536 x 64 (K=64), MFMA bf16, f32 out.
__device__ void u_body(const float* __restrict__ xc, const float* __restrict__ W0,
                       float* __restrict__ U, int ublk, int tid, char* smem) {
  unsigned short* a_lds = (unsigned short*)smem;                       // [128][72]
  unsigned short* w_lds = (unsigned short*)(smem + 128 * kLdsK * 2);   // [64][72]
  const int r0 = ublk * 128;
  {
    const int pt = tid >> 1, half = tid & 1;
    const float4* src = (const float4*)(xc + ((size_t)(r0 + pt)) * 64 + half * 32);
    unsigned* dst = (unsigned*)(a_lds + pt * kLdsK + half * 32);
#pragma unroll
    for (int i = 0; i < 8; ++i) {
      const float4 v = src[i];
      dst[2 * i + 0] = pack2bf(v.x, v.y);
      dst[2 * i + 1] = pack2bf(v.z, v.w);
    }
  }
  for (int e = tid; e < 64 * 64; e += 256) {
    const int d = e >> 6, k2 = e & 63;
    w_lds[d * kLdsK + k2] = f2bf(W0[d * kCF + 3 + k2]);
  }
  __syncthreads();
  const int w = tid >> 6, lane = tid & 63, lr = lane & 15, lk = lane >> 4;
  f32x4 acc[2][4];
#pragma unroll
  for (int mi = 0; mi < 2; ++mi)
#pragma unroll
    for (int ni = 0; ni < 4; ++ni) acc[mi][ni] = (f32x4){0.f, 0.f, 0.f, 0.f};
#pragma unroll
  for (int ks = 0; ks < 2; ++ks) {
    const int k = lk * 8 + ks * 32;
    const bf16x8 a0 = *(const bf16x8*)(a_lds + (32 * w + lr) * kLdsK + k);
    const bf16x8 a1 = *(const bf16x8*)(a_lds + (32 * w + 16 + lr) * kLdsK + k);
#pragma unroll
    for (int ni = 0; ni < 4; ++ni) {
      const bf16x8 bv = *(const bf16x8*)(w_lds + (16 * ni + lr) * kLdsK + k);
      acc[0][ni] = __builtin_amdgcn_mfma_f32_16x16x32_bf16(a0, bv, acc[0][ni], 0, 0, 0);
      acc[1][ni] = __builtin_amdgcn_mfma_f32_16x16x32_bf16(a1, bv, acc[1][ni], 0, 0, 0);
    }
  }
#pragma unroll
  for (int mi = 0; mi < 2; ++mi)
#pragma unroll
    for (int ni = 0; ni < 4; ++ni)
#pragma unroll
      for (int r = 0; r < 4; ++r) {
        const int row = 32 * w + 16 * mi + lk * 4 + r;
        U[((size_t)(r0 + row)) * 64 + 16 * ni + lr] = acc[mi][ni][r];
      }
}

__global__ __launch_bounds__(256) void k1_kernel(const float* __restrict__ x,
                                                 const float* __restrict__ xc,
                                                 const float* __restrict__ W0,
                                                 float* __restrict__ nxyz,
                                                 float* __restrict__ U) {
  __shared__ __align__(16) char smem[49664];
  if (blockIdx.x < 16) fps_body(x, nxyz, blockIdx.x, threadIdx.x, smem);
  else u_body(xc, W0, U, blockIdx.x - 16, threadIdx.x, smem);
}

// ---------------------------------------------------------- ball query ----
__global__ __launch_bounds__(256) void ballq_kernel(const float* __restrict__ x,
                                                    const float* __restrict__ new_xyz,
                                                    int* __restrict__ idx) {
  const int g = blockIdx.x * 4 + (threadIdx.x >> 6);
  const int lane = threadIdx.x & 63;
  const int b = g >> 10;
  const float* xb = x + (size_t)b * kN * 3;
  const float nx = new_xyz[g * 3 + 0];
  const float ny = new_xyz[g * 3 + 1];
  const float nz = new_xyz[g * 3 + 2];
  const float RR = (float)(0.2 * 0.2);
  int cnt = 0;
  int first = -1;
  for (int c = 0; c < kN / 64 && cnt < kK; ++c) {
    const int p = c * 64 + lane;
    const float dx = __fsub_rn(xb[p * 3 + 0], nx);
    const float dy = __fsub_rn(xb[p * 3 + 1], ny);
    const float dz = __fsub_rn(xb[p * 3 + 2], nz);
    const float t = __fadd_rn(__fadd_rn(__fmul_rn(dx, dx), __fmul_rn(dy, dy)),
                              __fmul_rn(dz, dz));
    const bool within = (t <= RR);
    const unsigned long long m = __ballot(within);
    if (first < 0 && m != 0ull) first = c * 64 + __builtin_ctzll(m);
    const int pos = cnt + (int)__popcll(m & ((1ull << lane) - 1ull));
    if (within && pos < kK) idx[(size_t)g * kK + pos] = p;
    cnt += (int)__popcll(m);
  }
  for (int k2 = cnt + lane; k2 < kK; k2 += 64) idx[(size_t)g * kK + k2] = first;
}

// ----------------------------------------------------- stats0 (y0 BN) ----
// y0 = U[v] + rel.W0xyz + b0; per-thread register accumulation over 8 pts.
__global__ __launch_bounds__(256) void stats0_kernel(
    const float* __restrict__ x, const float* __restrict__ nxyz,
    const int* __restrict__ idx, const float* __restrict__ U,
    const float* __restrict__ W0, const float* __restrict__ b0,
    float* __restrict__ stats) {
  __shared__ float4 w0c[64];
  __shared__ float red[128];
  const int tid = threadIdx.x;
  if (tid < 64) w0c[tid] = make_float4(W0[tid * kCF + 0], W0[tid * kCF + 1],
                                       W0[tid * kCF + 2], b0[tid]);
  if (tid < 128) red[tid] = 0.0f;
  __syncthreads();
  const int gid = blockIdx.x * 256 + tid;
  const int half = gid & 1;
  const int pbase = gid >> 1;  // [0, 65536)
  float s[32], q[32];
#pragma unroll
  for (int i = 0; i < 32; ++i) { s[i] = 0.f; q[i] = 0.f; }
  for (int r = 0; r < 8; ++r) {
    const int pt = pbase + r * 65536;
    const int v = idx[pt];
    const int b = pt >> 15;
    const int sc = (pt & (kSK - 1)) >> 5;
    const float* xp = x + ((size_t)b * kN + v) * 3;
    const float* np = nxyz + ((size_t)b * kS + sc) * 3;
    const float rx = xp[0] - np[0], ry = xp[1] - np[1], rz = xp[2] - np[2];
    const float4* up = (const float4*)(U + ((size_t)b * kN + v) * 64 + half * 32);
#pragma unroll
    for (int i = 0; i < 8; ++i) {
      const float4 u4 = up[i];
      const float uu[4] = {u4.x, u4.y, u4.z, u4.w};
#pragma unroll
      for (int j = 0; j < 4; ++j) {
        const float4 wc = w0c[half * 32 + i * 4 + j];
        const float y = uu[j] + rx * wc.x + ry * wc.y + rz * wc.z + wc.w;
        s[i * 4 + j] += y;
        q[i * 4 + j] += y * y;
      }
    }
  }
#pragma unroll
  for (int i = 0; i < 32; ++i) {
    const int c = half * 32 + i;
    atomicAdd(&red[c], s[i]);
    atomicAdd(&red[64 + c], q[i]);
  }
  __syncthreads();
  if (tid < 128) atomicAdd(&stats[tid], red[tid]);
}

// ----------------------------------------------------------- MLP pass ----
// STAGE 1: y0->a1->GEMM1 -> stats1.  STAGE 2: ...->GEMM2 -> stats2.
// STAGE 3: ...->bn2+relu -> maxpool(K=32) -> out.
template <int STAGE>
__global__ __launch_bounds__(256) void mlp_kernel(
    const float* __restrict__ x, const float* __restrict__ nxyz,
    const int* __restrict__ idx, const float* __restrict__ U,
    const float* __restrict__ W0, const float* __restrict__ b0,
    const float* __restrict__ W1, const float* __restrict__ b1v,
    const float* __restrict__ W2, const float* __restrict__ b2v,
    const float* __restrict__ scsh, float* __restrict__ stats,
    float* __restrict__ out) {
  __shared__ unsigned short a_lds[128 * kLdsK];
  __shared__ unsigned short w_lds[128 * kLdsK];
  __shared__ float red[256];
  __shared__ float4 w0c[64];
  __shared__ float2 sc0l[64];
  const int tid = threadIdx.x;
  const int p0 = blockIdx.x * 128;
  red[tid] = 0.0f;
  if (tid < 64) {
    w0c[tid] = make_float4(W0[tid * kCF + 0], W0[tid * kCF + 1],
                           W0[tid * kCF + 2], b0[tid]);
    sc0l[tid] = make_float2(scsh[tid], scsh[64 + tid]);
  }
  // stage W1 (bf16, padded stride)
  for (int f = tid; f < 64 * 16; f += 256) {
    const int d = f >> 4, k4 = (f & 15) * 4;
    const float4 vw = *(const float4*)(W1 + d * 64 + k4);
    unsigned* dst = (unsigned*)(w_lds + d * kLdsK + k4);
    dst[0] = pack2bf(vw.x, vw.y);
    dst[1] = pack2bf(vw.z, vw.w);
  }
  __syncthreads();

  {  // gather + y0 + bn0 + relu -> a_lds (bf16)
    const int pt = tid >> 1, half = tid & 1;
    const int pg = p0 + pt;
    const int v = idx[pg];
    const int b = pg >> 15;
    const int sct = (pg & (kSK - 1)) >> 5;
    const float* xp = x + ((size_t)b * kN + v) * 3;
    const float* np = nxyz + ((size_t)b * kS + sct) * 3;
    const float rx = xp[0] - np[0], ry = xp[1] - np[1], rz = xp[2] - np[2];
    const float4* up = (const float4*)(U + ((size_t)b * kN + v) * 64 + half * 32);
    unsigned* dst = (unsigned*)(a_lds + pt * kLdsK + half * 32);
#pragma unroll
    for (int i = 0; i < 8; ++i) {
      const float4 u4 = up[i];
      const float uu[4] = {u4.x, u4.y, u4.z, u4.w};
      float a1[4];
#pragma unroll
      for (int j = 0; j < 4; ++j) {
        const int c = half * 32 + i * 4 + j;
        const float4 wc = w0c[c];
        const float y = uu[j] + rx * wc.x + ry * wc.y + rz * wc.z + wc.w;
        const float2 ss = sc0l[c];
        a1[j] = fmaxf(fmaf(y, ss.x, ss.y), 0.0f);
      }
      dst[2 * i + 0] = pack2bf(a1[0], a1[1]);
      dst[2 * i + 1] = pack2bf(a1[2], a1[3]);
    }
  }
  __syncthreads();

  const int w = tid >> 6, lane = tid & 63, lr = lane & 15, lk = lane >> 4;

  f32x4 acc1[2][4];
#pragma unroll
  for (int mi = 0; mi < 2; ++mi)
#pragma unroll
    for (int ni = 0; ni < 4; ++ni) acc1[mi][ni] = (f32x4){0.f, 0.f, 0.f, 0.f};
#pragma unroll
  for (int ks = 0; ks < 2; ++ks) {
    const int k = lk * 8 + ks * 32;
    const bf16x8 a0 = *(const bf16x8*)(a_lds + (32 * w + lr) * kLdsK + k);
    const bf16x8 a1 = *(const bf16x8*)(a_lds + (32 * w + 16 + lr) * kLdsK + k);
#pragma unroll
    for (int ni = 0; ni < 4; ++ni) {
      const bf16x8 bv = *(const bf16x8*)(w_lds + (16 * ni + lr) * kLdsK + k);
      acc1[0][ni] = __builtin_amdgcn_mfma_f32_16x16x32_bf16(a0, bv, acc1[0][ni], 0, 0, 0);
      acc1[1][ni] = __builtin_amdgcn_mfma_f32_16x16x32_bf16(a1, bv, acc1[1][ni], 0, 0, 0);
    }
  }

  if constexpr (STAGE == 1) {
#pragma unroll
    for (int ni = 0; ni < 4; ++ni) {
      const int ch = 16 * ni + lr;
      const float bb = b1v[ch];
      float ss = 0.f, qq = 0.f;
#pragma unroll
      for (int mi = 0; mi < 2; ++mi)
#pragma unroll
        for (int r = 0; r < 4; ++r) {
          const float y = acc1[mi][ni][r] + bb;
          ss += y;
          qq += y * y;
        }
      atomicAdd(&red[ch], ss);
      atomicAdd(&red[64 + ch], qq);
    }
    __syncthreads();
    if (tid < 128) atomicAdd(&stats[128 + tid], red[tid]);
    return;
  } else {
    __syncthreads();  // all GEMM1 reads of w_lds done
    // a2 = relu(bn1(acc1 + b1)) -> a_lds (wave-own rows)
#pragma unroll
    for (int ni = 0; ni < 4; ++ni) {
      const int ch = 16 * ni + lr;
      const float bb = b1v[ch];
      const float sc1 = scsh[128 + ch], sh1 = scsh[192 + ch];
#pragma unroll
      for (int mi = 0; mi < 2; ++mi)
#pragma unroll
        for (int r = 0; r < 4; ++r) {
          const int row = 32 * w + 16 * mi + lk * 4 + r;
          const float val = fmaxf(fmaf(acc1[mi][ni][r] + bb, sc1, sh1), 0.0f);
          a_lds[row * kLdsK + ch] = f2bf(val);
        }
    }
    // stage W2
    for (int f = tid; f < 128 * 16; f += 256) {
      const int d = f >> 4, k4 = (f & 15) * 4;
      const float4 vw = *(const float4*)(W2 + d * 64 + k4);
      unsigned* dst = (unsigned*)(w_lds + d * kLdsK + k4);
      dst[0] = pack2bf(vw.x, vw.y);
      dst[1] = pack2bf(vw.z, vw.w);
    }
    __syncthreads();

    f32x4 acc2[2][8];
#pragma unroll
    for (int mi = 0; mi < 2; ++mi)
#pragma unroll
      for (int ni = 0; ni < 8; ++ni) acc2[mi][ni] = (f32x4){0.f, 0.f, 0.f, 0.f};
#pragma unroll
    for (int ks = 0; ks < 2; ++ks) {
      const int k = lk * 8 + ks * 32;
      const bf16x8 a0 = *(const bf16x8*)(a_lds + (32 * w + lr) * kLdsK + k);
      const bf16x8 a1 = *(const bf16x8*)(a_lds + (32 * w + 16 + lr) * kLdsK + k);
#pragma unroll
      for (int ni = 0; ni < 8; ++ni) {
        const bf16x8 bv = *(const bf16x8*)(w_lds + (16 * ni + lr) * kLdsK + k);
        acc2[0][ni] = __builtin_amdgcn_mfma_f32_16x16x32_bf16(a0, bv, acc2[0][ni], 0, 0, 0);
        acc2[1][ni] = __builtin_amdgcn_mfma_f32_16x16x32_bf16(a1, bv, acc2[1][ni], 0, 0, 0);
      }
    }

    if constexpr (STAGE == 2) {
#pragma unroll
      for (int ni = 0; ni < 8; ++ni) {
        const int ch = 16 * ni + lr;
        const float bb = b2v[ch];
        float ss = 0.f, qq = 0.f;
#pragma unroll
        for (int mi = 0; mi < 2; ++mi)
#pragma unroll
          for (int r = 0; r < 4; ++r) {
            const float y = acc2[mi][ni][r] + bb;
            ss += y;
            qq += y * y;
          }
        atomicAdd(&red[ch], ss);
        atomicAdd(&red[128 + ch], qq);
      }
      __syncthreads();
      atomicAdd(&stats[256 + tid], red[tid]);
    } else {
      // STAGE 3: bn2+relu, maxpool over the wave's 32 rows (one group)
      float mx[8];
#pragma unroll
      for (int ni = 0; ni < 8; ++ni) {
        const int ch = 16 * ni + lr;
        const float bb = b2v[ch];
        const float sc2 = scsh[256 + ch], sh2 = scsh[384 + ch];
        float m = -1.0f;
#pragma unroll
        for (int mi = 0; mi < 2; ++mi)
#pragma unroll
          for (int r = 0; r < 4; ++r)
            m = fmaxf(m, fmaxf(fmaf(acc2[mi][ni][r] + bb, sc2, sh2), 0.0f));
        mx[ni] = m;
      }
#pragma unroll
      for (int ni = 0; ni < 8; ++ni) {
        mx[ni] = fmaxf(mx[ni], __shfl_xor(mx[ni], 16, 64));
        mx[ni] = fmaxf(mx[ni], __shfl_xor(mx[ni], 32, 64));
      }
      const int pg0 = p0 + 32 * w;
      const int ob = pg0 >> 15;
      const int os = (pg0 & (kSK - 1)) >> 5;
      if (lane < 16) {
#pragma unroll
        for (int ni = 0; ni < 8; ++ni)
          out[((size_t)ob * 128 + 16 * ni + lane) * kS + os] = mx[ni];
      }
    }
  }
}

// ------------------------------------------------------------ finalize ----
__global__ void finalize_kernel(const float* __restrict__ g, const float* __restrict__ be,
                                const float* __restrict__ st, float* __restrict__ sc,
                                float* __restrict__ sh, int C) {
  const int c = threadIdx.x;
  if (c < C) {
    const float mean = st[c] / kM;
    const float var = st[C + c] / kM - mean * mean;
    const float scale = g[c] / sqrtf(var + 1e-5f);
    sc[c] = scale;
    sh[c] = be[c] - mean * scale;
  }
}

// =================== FALLBACK (small ws): round-2 recompute path ==========
__device__ __forceinline__ void load_bias4(float acc[4][4], const float* b, int tc) {
  const float4 bv = *(const float4*)(b + tc * 4);
  const float bb[4] = {bv.x, bv.y, bv.z, bv.w};
#pragma unroll
  for (int p2 = 0; p2 < 4; ++p2)
#pragma unroll
    for (int ci = 0; ci < 4; ++ci) acc[p2][ci] = bb[ci];
}

__device__ __forceinline__ void gemm4x4(const float* f_lds, const float* w_lds,
                                        int J, int tr, int tc, float acc[4][4]) {
  for (int j = 0; j < J; ++j) {
    const float4 w = *(const float4*)(w_lds + j * 64 + tc * 4);
#pragma unroll
    for (int p2 = 0; p2 < 4; ++p2) {
      const float fv = f_lds[(tr * 4 + p2) * kFD + j];
      acc[p2][0] = fmaf(fv, w.x, acc[p2][0]);
      acc[p2][1] = fmaf(fv, w.y, acc[p2][1]);
      acc[p2][2] = fmaf(fv, w.z, acc[p2][2]);
      acc[p2][3] = fmaf(fv, w.w, acc[p2][3]);
    }
  }
}

__device__ __forceinline__ void bnrelu4(float acc[4][4], const float* scp,
                                        const float* shp, int tc) {
  const float4 s4 = *(const float4*)(scp + tc * 4);
  const float4 h4 = *(const float4*)(shp + tc * 4);
  const float sv[4] = {s4.x, s4.y, s4.z, s4.w};
  const float hv[4] = {h4.x, h4.y, h4.z, h4.w};
#pragma unroll
  for (int p2 = 0; p2 < 4; ++p2)
#pragma unroll
    for (int ci = 0; ci < 4; ++ci)
      acc[p2][ci] = fmaxf(fmaf(acc[p2][ci], sv[ci], hv[ci]), 0.0f);
}

__device__ __forceinline__ void store_a4(const float acc[4][4], float* f_lds,
                                         int tr, int tc) {
#pragma unroll
  for (int p2 = 0; p2 < 4; ++p2)
#pragma unroll
    for (int ci = 0; ci < 4; ++ci)
      f_lds[(tr * 4 + p2) * kFD + tc * 4 + ci] = acc[p2][ci];
}

__device__ __forceinline__ void block_stats4(const float acc[4][4], float* red,
                                             int tc, int C) {
#pragma unroll
  for (int ci = 0; ci < 4; ++ci) {
    const int c = tc * 4 + ci;
    const float sv = acc[0][ci] + acc[1][ci] + acc[2][ci] + acc[3][ci];
    const float qv = acc[0][ci] * acc[0][ci] + acc[1][ci] * acc[1][ci] +
                     acc[2][ci] * acc[2][ci] + acc[3][ci] * acc[3][ci];
    atomicAdd(&red[c], sv);
    atomicAdd(&red[C + c], qv);
  }
}

__device__ __forceinline__ void gather_f(const float* __restrict__ x,
                                         const float* __restrict__ xc,
                                         const float* __restrict__ nxyz,
                                         const int* __restrict__ idx,
                                         float* f_lds, int p0, int tid) {
  const int th_p = tid >> 2;
  const int th_i = tid & 3;
  const int pg = p0 + th_p;
  const int b = pg >> 15;
  const int r = pg & (kSK - 1);
  const int s = r >> 5;
  const int v = idx[pg];
  const float4* feat = (const float4*)(xc + ((size_t)b * kN + v) * kCIN) + th_i * 4;
  const float4 q0 = feat[0], q1 = feat[1], q2 = feat[2], q3 = feat[3];
  float* dst = f_lds + th_p * kFD + 3 + th_i * 16;
  dst[0] = q0.x; dst[1] = q0.y; dst[2] = q0.z; dst[3] = q0.w;
  dst[4] = q1.x; dst[5] = q1.y; dst[6] = q1.z; dst[7] = q1.w;
  dst[8] = q2.x; dst[9] = q2.y; dst[10] = q2.z; dst[11] = q2.w;
  dst[12] = q3.x; dst[13] = q3.y; dst[14] = q3.z; dst[15] = q3.w;
  if (th_i == 0) {
    const float* xp = x + ((size_t)b * kN + v) * 3;
    const float* np = nxyz + ((size_t)b * kS + s) * 3;
    float* fr = f_lds + th_p * kFD;
    fr[0] = __fsub_rn(xp[0], np[0]);
    fr[1] = __fsub_rn(xp[1], np[1]);
    fr[2] = __fsub_rn(xp[2], np[2]);
  }
}

template <int STAGE>
__global__ __launch_bounds__(256) void pass_kernel(
    const float* __restrict__ x, const float* __restrict__ xc,
    const float* __restrict__ W0, const float* __restrict__ b0,
    const float* __restrict__ W1, const float* __restrict__ b1,
    const float* __restrict__ W2, const float* __restrict__ b2,
    const float* __restrict__ nxyz, const int* __restrict__ idx,
    const float* __restrict__ scsh, float* __restrict__ stats,
    float* __restrict__ out) {
  __shared__ float f_lds[64 * kFD];
  __shared__ float w_lds[64 * 128];
  __shared__ float red[256];
  const int tid = threadIdx.x;
  const int p0 = blockIdx.x * 64;
  red[tid] = 0.0f;
  gather_f(x, xc, nxyz, idx, f_lds, p0, tid);
  for (int q = tid; q < 64 * kCF; q += 256) {
    const int c = q / kCF;
    const int j = q - c * kCF;
    w_lds[j * 64 + c] = W0[q];
  }
  __syncthreads();

  const int tc = tid & 15;
  const int tr = tid >> 4;

  float acc[4][4];
  load_bias4(acc, b0, tc);
  gemm4x4(f_lds, w_lds, kCF, tr, tc, acc);

  if constexpr (STAGE == 0) {
    block_stats4(acc, red, tc, 64);
    __syncthreads();
    if (tid < 128) atomicAdd(&stats[tid], red[tid]);
    return;
  } else {
    bnrelu4(acc, scsh + 0, scsh + 64, tc);
    __syncthreads();
    store_a4(acc, f_lds, tr, tc);
    for (int q = tid; q < 64 * 64; q += 256) {
      const int c = q >> 6, j = q & 63;
      w_lds[j * 64 + c] = W1[q];
    }
    __syncthreads();

    load_bias4(acc, b1, tc);
    gemm4x4(f_lds, w_lds, 64, tr, tc, acc);

    if constexpr (STAGE == 1) {
      block_stats4(acc, red, tc, 64);
      __syncthreads();
      if (tid < 128) atomicAdd(&stats[128 + tid], red[tid]);
      return;
    } else {
      bnrelu4(acc, scsh + 128, scsh + 192, tc);
      __syncthreads();
      store_a4(acc, f_lds, tr, tc);
      for (int q = tid; q < 128 * 64; q += 256) {
        const int c = q >> 6, j = q & 63;
        w_lds[j * 128 + c] = W2[q];
      }
      __syncthreads();

      const int c0 = tc * 8;
      float acc2[4][8];
      {
        const float4 ba = *(const float4*)(b2 + c0);
        const float4 bb = *(const float4*)(b2 + c0 + 4);
        const float bv[8] = {ba.x, ba.y, ba.z, ba.w, bb.x, bb.y, bb.z, bb.w};
#pragma unroll
        for (int p2 = 0; p2 < 4; ++p2)
#pragma unroll
          for (int ci = 0; ci < 8; ++ci) acc2[p2][ci] = bv[ci];
      }
      for (int j = 0; j < 64; ++j) {
        const float4 wa = *(const float4*)(w_lds + j * 128 + c0);
        const float4 wb = *(const float4*)(w_lds + j * 128 + c0 + 4);
#pragma unroll
        for (int p2 = 0; p2 < 4; ++p2) {
          const float fv = f_lds[(tr * 4 + p2) * kFD + j];
          acc2[p2][0] = fmaf(fv, wa.x, acc2[p2][0]);
          acc2[p2][1] = fmaf(fv, wa.y, acc2[p2][1]);
          acc2[p2][2] = fmaf(fv, wa.z, acc2[p2][2]);
          acc2[p2][3] = fmaf(fv, wa.w, acc2[p2][3]);
          acc2[p2][4] = fmaf(fv, wb.x, acc2[p2][4]);
          acc2[p2][5] = fmaf(fv, wb.y, acc2[p2][5]);
          acc2[p2][6] = fmaf(fv, wb.z, acc2[p2][6]);
          acc2[p2][7] = fmaf(fv, wb.w, acc2[p2][7]);
        }
      }

      if constexpr (STAGE == 2) {
#pragma unroll
        for (int ci = 0; ci < 8; ++ci) {
          const int c = c0 + ci;
          const float sv = acc2[0][ci] + acc2[1][ci] + acc2[2][ci] + acc2[3][ci];
          const float qv = acc2[0][ci] * acc2[0][ci] + acc2[1][ci] * acc2[1][ci] +
                           acc2[2][ci] * acc2[2][ci] + acc2[3][ci] * acc2[3][ci];
          atomicAdd(&red[c], sv);
          atomicAdd(&red[128 + c], qv);
        }
        __syncthreads();
        atomicAdd(&stats[256 + tid], red[tid]);
        return;
      } else {
        const float4 sa = *(const float4*)(scsh + 256 + c0);
        const float4 sb = *(const float4*)(scsh + 256 + c0 + 4);
        const float4 ha = *(const float4*)(scsh + 384 + c0);
        const float4 hb = *(const float4*)(scsh + 384 + c0 + 4);
        const float scv[8] = {sa.x, sa.y, sa.z, sa.w, sb.x, sb.y, sb.z, sb.w};
        const float shv[8] = {ha.x, ha.y, ha.z, ha.w, hb.x, hb.y, hb.z, hb.w};
        unsigned* redu = (unsigned*)red;
        const int grp = tr >> 3;
#pragma unroll
        for (int ci = 0; ci < 8; ++ci) {
          const float m0 = fmaxf(fmaf(acc2[0][ci], scv[ci], shv[ci]), 0.0f);
          const float m1 = fmaxf(fmaf(acc2[1][ci], scv[ci], shv[ci]), 0.0f);
          const float m2 = fmaxf(fmaf(acc2[2][ci], scv[ci], shv[ci]), 0.0f);
          const float m3 = fmaxf(fmaf(acc2[3][ci], scv[ci], shv[ci]), 0.0f);
          const float mm = fmaxf(fmaxf(m0, m1), fmaxf(m2, m3));
          atomicMax(&redu[grp * 128 + c0 + ci], __float_as_uint(mm));
        }
        __syncthreads();
        const int sg = (p0 >> 5) + (tid >> 7);
        const int ob = sg >> 10;
        const int os = sg & 1023;
        out[((size_t)ob * 128 + (tid & 127)) * kS + os] =
            __uint_as_float(((unsigned*)red)[tid]);
      }
    }
  }
}

// --------------------------------------------------------------- launch ----
extern "C" void kernel_launch(void* const* d_in, const int* in_sizes, int n_in,
                              void* d_out, int out_size, void* d_ws, size_t ws_size,
                              hipStream_t stream) {
  const float* x   = (const float*)d_in[0];
  const float* xc  = (const float*)d_in[1];
  const float* W0  = (const float*)d_in[2];
  const float* b0  = (const float*)d_in[3];
  const float* g0  = (const float*)d_in[4];
  const float* be0 = (const float*)d_in[5];
  const float* W1  = (const float*)d_in[6];
  const float* b1  = (const float*)d_in[7];
  const float* g1  = (const float*)d_in[8];
  const float* be1 = (const float*)d_in[9];
  const float* W2  = (const float*)d_in[10];
  const float* b2  = (const float*)d_in[11];
  const float* g2  = (const float*)d_in[12];
  const float* be2 = (const float*)d_in[13];
  float* out = (float*)d_out;
  char* ws = (char*)d_ws;
  float* nxyz  = (float*)(ws);
  int*   idx   = (int*)(ws + kOffIdx);
  float* stats = (float*)(ws + kOffStats);
  float* scsh  = (float*)(ws + kOffScsh);
  float* U     = (float*)(ws + kOffU);
  (void)in_sizes; (void)n_in; (void)out_size;

  hipMemsetAsync(stats, 0, 512 * sizeof(float), stream);

  if (ws_size >= kWsNeedU) {
    k1_kernel<<<16 + 512, 256, 0, stream>>>(x, xc, W0, nxyz, U);
    ballq_kernel<<<(kB * kS) / 4, 256, 0, stream>>>(x, nxyz, idx);
    stats0_kernel<<<512, 256, 0, stream>>>(x, nxyz, idx, U, W0, b0, stats);
    finalize_kernel<<<1, 128, 0, stream>>>(g0, be0, stats, scsh, scsh + 64, 64);
    mlp_kernel<1><<<kPT / 128, 256, 0, stream>>>(x, nxyz, idx, U, W0, b0, W1, b1,
                                                 W2, b2, scsh, stats, out);
    finalize_kernel<<<1, 128, 0, stream>>>(g1, be1, stats + 128, scsh + 128, scsh + 192, 64);
    mlp_kernel<2><<<kPT / 128, 256, 0, stream>>>(x, nxyz, idx, U, W0, b0, W1, b1,
                                                 W2, b2, scsh, stats, out);
    finalize_kernel<<<1, 128, 0, stream>>>(g2, be2, stats + 256, scsh + 256, scsh + 384, 128);
    mlp_kernel<3><<<kPT / 128, 256, 0, stream>>>(x, nxyz, idx, U, W0, b0, W1, b1,
                                                 W2, b2, scsh, stats, out);
  } else {
    k1_kernel<<<16, 256, 0, stream>>>(x, xc, W0, nxyz, nxyz);
    ballq_kernel<<<(kB * kS) / 4, 256, 0, stream>>>(x, nxyz, idx);
    pass_kernel<0><<<kPT / 64, 256, 0, stream>>>(x, xc, W0, b0, W1, b1, W2, b2,
                                                 nxyz, idx, scsh, stats, out);
    finalize_kernel<<<1, 128, 0, stream>>>(g0, be0, stats, scsh, scsh + 64, 64);
    pass_kernel<1><<<kPT / 64, 256, 0, stream>>>(x, xc, W0, b0, W1, b1, W2, b2,
                                                 nxyz, idx, scsh, stats, out);
    finalize_kernel<<<1, 128, 0, stream>>>(g1, be1, stats + 128, scsh + 128, scsh + 192, 64);
    pass_kernel<2><<<kPT / 64, 256, 0, stream>>>(x, xc, W0, b0, W1, b1, W2, b2,
                                                 nxyz, idx, scsh, stats, out);
    finalize_kernel<<<1, 128, 0, stream>>>(g2, be2, stats + 256, scsh + 256, scsh + 384, 128);
    pass_kernel<3><<<kPT / 64, 256, 0, stream>>>(x, xc, W0, b0, W1, b1, W2, b2,
                                                 nxyz, idx, scsh, stats, out);
  }
}

// Round 6
// 1187.499 us; speedup vs baseline: 2.8193x; 1.1064x over previous
//
#include <hip/hip_runtime.h>

namespace {
constexpr int kB = 16;
constexpr int kN = 4096;
constexpr int kS = 1024;
constexpr int kK = 32;
constexpr int kCF = 67;   // 3 + 64
constexpr int kSK = kS * kK;      // 32768
constexpr int kPT = kB * kSK;     // 524288
constexpr float kM = 524288.0f;   // BN count per channel

constexpr size_t kOffIdx   = 196608;
constexpr size_t kOffStats = 2293760;
constexpr size_t kOffScsh  = 2295808;
constexpr size_t kOffU     = 2297856;
constexpr size_t kWsNeedU  = kOffU + (size_t)kB * kN * 64 * sizeof(float);  // 19075072
constexpr size_t kOffPmax  = 19075072;                       // 8388608 B
constexpr size_t kOffPmin  = kOffPmax + 8388608;             // 8388608 B
constexpr size_t kOffY1    = kOffPmin + 8388608;             // 35852288
constexpr size_t kWsNeedF  = kOffY1 + (size_t)kPT * 64 * 2;  // 102961152

constexpr int kLdsK = 72;  // bf16 row stride: 144 B (16B-aligned, 2-way banks)

using bf16x8 = __attribute__((ext_vector_type(8))) short;
using f32x4  = __attribute__((ext_vector_type(4))) float;
}

__device__ __forceinline__ unsigned short f2bf(float f) {
  unsigned u = __float_as_uint(f);
  u += 0x7fffu + ((u >> 16) & 1u);
  return (unsigned short)(u >> 16);
}
__device__ __forceinline__ unsigned pack2bf(float a, float b) {
  return (unsigned)f2bf(a) | ((unsigned)f2bf(b) << 16);
}

// DPP cross-lane helpers (VALU-speed, no LDS pipe). Canonical 64-lane
// reduce: row_shr 1/2/4/8 then row_bcast15(rows1,3) + row_bcast31(rows2,3);
// full result lands in lane 63.
template <int CTRL, int RM>
__device__ __forceinline__ float fmax_dpp(float x) {
  const int m = __builtin_amdgcn_update_dpp(__float_as_int(x), __float_as_int(x),
                                            CTRL, RM, 0xf, false);
  return fmaxf(x, __int_as_float(m));
}
template <int CTRL, int RM>
__device__ __forceinline__ unsigned umin_dpp(unsigned x) {
  const unsigned m = (unsigned)__builtin_amdgcn_update_dpp((int)x, (int)x,
                                                           CTRL, RM, 0xf, false);
  return x < m ? x : m;
}

// ---------------------------------------------------------------- FPS ----
// 4 waves, 16 contiguous pts/lane in registers. rn-exact dist update; wave
// max + first-occurrence index via DPP (lane order == index order).
__device__ void fps_body(const float* __restrict__ x, float* __restrict__ new_xyz,
                         int b, int tid, char* smem) {
  float* xs = (float*)smem;
  float* ys = xs + kN;
  float* zs = ys + kN;
  float* pv = zs + kN;           // [2][4]
  int*   pi = (int*)(pv + 8);    // [2][4]
  const int lane = tid & 63;
  const int wid = tid >> 6;
  const float* xb = x + (size_t)b * kN * 3;
  for (int q = tid; q < kN; q += 256) {
    xs[q] = xb[q * 3 + 0];
    ys[q] = xb[q * 3 + 1];
    zs[q] = xb[q * 3 + 2];
  }
  __syncthreads();
  float px[16], py[16], pz[16], dm[16];
#pragma unroll
  for (int j = 0; j < 16; ++j) {
    const int p = tid * 16 + j;
    px[j] = xs[p]; py[j] = ys[p]; pz[j] = zs[p];
    dm[j] = 1e10f;
  }
  int far = 0;
  for (int i = 0; i < kS; ++i) {
    const float cx = xs[far], cy = ys[far], cz = zs[far];
    if (tid == 0) {
      float* o = new_xyz + ((size_t)b * kS + i) * 3;
      o[0] = cx; o[1] = cy; o[2] = cz;
    }
#pragma unroll
    for (int j = 0; j < 16; ++j) {
      const float dx = __fsub_rn(px[j], cx);
      const float dy = __fsub_rn(py[j], cy);
      const float dz = __fsub_rn(pz[j], cz);
      const float t = __fadd_rn(__fadd_rn(__fmul_rn(dx, dx), __fmul_rn(dy, dy)),
                                __fmul_rn(dz, dz));
      dm[j] = fminf(dm[j], t);
    }
    // in-lane max (max3-friendly triples)
    const float m0 = fmaxf(fmaxf(dm[0], dm[1]), dm[2]);
    const float m1 = fmaxf(fmaxf(dm[3], dm[4]), dm[5]);
    const float m2 = fmaxf(fmaxf(dm[6], dm[7]), dm[8]);
    const float m3 = fmaxf(fmaxf(dm[9], dm[10]), dm[11]);
    const float m4 = fmaxf(fmaxf(dm[12], dm[13]), dm[14]);
    const float n0 = fmaxf(fmaxf(m0, m1), dm[15]);
    const float n1 = fmaxf(fmaxf(m2, m3), m4);
    float v = fmaxf(n0, n1);
    // wave max via DPP
    v = fmax_dpp<0x111, 0xf>(v);
    v = fmax_dpp<0x112, 0xf>(v);
    v = fmax_dpp<0x114, 0xf>(v);
    v = fmax_dpp<0x118, 0xf>(v);
    v = fmax_dpp<0x142, 0xa>(v);
    v = fmax_dpp<0x143, 0xc>(v);
    const float wv = __int_as_float(__builtin_amdgcn_readlane(__float_as_int(v), 63));
    // first-occurrence global index via u32 wave-min
    unsigned msk = 0;
#pragma unroll
    for (int j = 0; j < 16; ++j) msk |= (dm[j] == wv ? 1u : 0u) << j;
    unsigned cand = msk ? ((unsigned)(tid * 16) + (unsigned)__builtin_ctz(msk))
                        : 0xffffffffu;
    cand = umin_dpp<0x111, 0xf>(cand);
    cand = umin_dpp<0x112, 0xf>(cand);
    cand = umin_dpp<0x114, 0xf>(cand);
    cand = umin_dpp<0x118, 0xf>(cand);
    cand = umin_dpp<0x142, 0xa>(cand);
    cand = umin_dpp<0x143, 0xc>(cand);
    const unsigned widx = (unsigned)__builtin_amdgcn_readlane((int)cand, 63);
    const int par = i & 1;
    if (lane == 0) { pv[par * 4 + wid] = wv; pi[par * 4 + wid] = (int)widx; }
    __syncthreads();
    float fv = pv[par * 4 + 0];
    int fi = pi[par * 4 + 0];
#pragma unroll
    for (int w = 1; w < 4; ++w) {
      const float v2 = pv[par * 4 + w];
      const int i2 = pi[par * 4 + w];
      if (v2 > fv) { fv = v2; fi = i2; }  // ascending wave: first-occurrence
    }
    far = fi;
  }
}

// --------------------------------------------- U = feat . W0[:,3:]^T ----
__device__ void u_body(const float* __restrict__ xc, const float* __restrict__ W0,
                       float* __restrict__ U, int ublk, int tid, char* smem) {
  unsigned short* a_lds = (unsigned short*)smem;                       // [128][72]
  unsigned short* w_lds = (unsigned short*)(smem + 128 * kLdsK * 2);   // [64][72]
  const int r0 = ublk * 128;
  {
    const int pt = tid >> 1, half = tid & 1;
    const float4* src = (const float4*)(xc + ((size_t)(r0 + pt)) * 64 + half * 32);
    unsigned* dst = (unsigned*)(a_lds + pt * kLdsK + half * 32);
#pragma unroll
    for (int i = 0; i < 8; ++i) {
      const float4 v = src[i];
      dst[2 * i + 0] = pack2bf(v.x, v.y);
      dst[2 * i + 1] = pack2bf(v.z, v.w);
    }
  }
  for (int e = tid; e < 64 * 64; e += 256) {
    const int d = e >> 6, k2 = e & 63;
    w_lds[d * kLdsK + k2] = f2bf(W0[d * kCF + 3 + k2]);
  }
  __syncthreads();
  const int w = tid >> 6, lane = tid & 63, lr = lane & 15, lk = lane >> 4;
  f32x4 acc[2][4];
#pragma unroll
  for (int mi = 0; mi < 2; ++mi)
#pragma unroll
    for (int ni = 0; ni < 4; ++ni) acc[mi][ni] = (f32x4){0.f, 0.f, 0.f, 0.f};
#pragma unroll
  for (int ks = 0; ks < 2; ++ks) {
    const int k = lk * 8 + ks * 32;
    const bf16x8 a0 = *(const bf16x8*)(a_lds + (32 * w + lr) * kLdsK + k);
    const bf16x8 a1 = *(const bf16x8*)(a_lds + (32 * w + 16 + lr) * kLdsK + k);
#pragma unroll
    for (int ni = 0; ni < 4; ++ni) {
      const bf16x8 bv = *(const bf16x8*)(w_lds + (16 * ni + lr) * kLdsK + k);
      acc[0][ni] = __builtin_amdgcn_mfma_f32_16x16x32_bf16(a0, bv, acc[0][ni], 0, 0, 0);
      acc[1][ni] = __builtin_amdgcn_mfma_f32_16x16x32_bf16(a1, bv, acc[1][ni], 0, 0, 0);
    }
  }
#pragma unroll
  for (int mi = 0; mi < 2; ++mi)
#pragma unroll
    for (int ni = 0; ni < 4; ++ni)
#pragma unroll
      for (int r = 0; r < 4; ++r) {
        const int row = 32 * w + 16 * mi + lk * 4 + r;
        U[((size_t)(r0 + row)) * 64 + 16 * ni + lr] = acc[mi][ni][r];
      }
}

__global__ __launch_bounds__(256) void k1_kernel(const float* __restrict__ x,
                                                 const float* __restrict__ xc,
                                                 const float* __restrict__ W0,
                                                 float* __restrict__ nxyz,
                                                 float* __restrict__ U) {
  __shared__ __align__(16) char smem[49664];
  if (blockIdx.x < 16) fps_body(x, nxyz, blockIdx.x, threadIdx.x, smem);
  else u_body(xc, W0, U, blockIdx.x - 16, threadIdx.x, smem);
}

// ---------------------------------------------------------- ball query ----
__global__ __launch_bounds__(256) void ballq_kernel(const float* __restrict__ x,
                                                    const float* __restrict__ new_xyz,
                                                    int* __restrict__ idx) {
  const int g = blockIdx.x * 4 + (threadIdx.x >> 6);
  const int lane = threadIdx.x & 63;
  const int b = g >> 10;
  const float* xb = x + (size_t)b * kN * 3;
  const float nx = new_xyz[g * 3 + 0];
  const float ny = new_xyz[g * 3 + 1];
  const float nz = new_xyz[g * 3 + 2];
  const float RR = (float)(0.2 * 0.2);
  int cnt = 0;
  int first = -1;
  for (int c = 0; c < kN / 64 && cnt < kK; ++c) {
    const int p = c * 64 + lane;
    const float dx = __fsub_rn(xb[p * 3 + 0], nx);
    const float dy = __fsub_rn(xb[p * 3 + 1], ny);
    const float dz = __fsub_rn(xb[p * 3 + 2], nz);
    const float t = __fadd_rn(__fadd_rn(__fmul_rn(dx, dx), __fmul_rn(dy, dy)),
                              __fmul_rn(dz, dz));
    const bool within = (t <= RR);
    const unsigned long long m = __ballot(within);
    if (first < 0 && m != 0ull) first = c * 64 + __builtin_ctzll(m);
    const int pos = cnt + (int)__popcll(m & ((1ull << lane) - 1ull));
    if (within && pos < kK) idx[(size_t)g * kK + pos] = p;
    cnt += (int)__popcll(m);
  }
  for (int k2 = cnt + lane; k2 < kK; k2 += 64) idx[(size_t)g * kK + k2] = first;
}

// ----------------------------------------------------- stats0 (y0 BN) ----
__global__ __launch_bounds__(256) void stats0_kernel(
    const float* __restrict__ x, const float* __restrict__ nxyz,
    const int* __restrict__ idx, const float* __restrict__ U,
    const float* __restrict__ W0, const float* __restrict__ b0,
    float* __restrict__ stats) {
  __shared__ float4 w0c[64];
  __shared__ float red[128];
  const int tid = threadIdx.x;
  if (tid < 64) w0c[tid] = make_float4(W0[tid * kCF + 0], W0[tid * kCF + 1],
                                       W0[tid * kCF + 2], b0[tid]);
  if (tid < 128) red[tid] = 0.0f;
  __syncthreads();
  const int gid = blockIdx.x * 256 + tid;
  const int half = gid & 1;
  const int pbase = gid >> 1;
  float s[32], q[32];
#pragma unroll
  for (int i = 0; i < 32; ++i) { s[i] = 0.f; q[i] = 0.f; }
  for (int r = 0; r < 8; ++r) {
    const int pt = pbase + r * 65536;
    const int v = idx[pt];
    const int b = pt >> 15;
    const int sc = (pt & (kSK - 1)) >> 5;
    const float* xp = x + ((size_t)b * kN + v) * 3;
    const float* np = nxyz + ((size_t)b * kS + sc) * 3;
    const float rx = xp[0] - np[0], ry = xp[1] - np[1], rz = xp[2] - np[2];
    const float4* up = (const float4*)(U + ((size_t)b * kN + v) * 64 + half * 32);
#pragma unroll
    for (int i = 0; i < 8; ++i) {
      const float4 u4 = up[i];
      const float uu[4] = {u4.x, u4.y, u4.z, u4.w};
#pragma unroll
      for (int j = 0; j < 4; ++j) {
        const float4 wc = w0c[half * 32 + i * 4 + j];
        const float y = uu[j] + rx * wc.x + ry * wc.y + rz * wc.z + wc.w;
        s[i * 4 + j] += y;
        q[i * 4 + j] += y * y;
      }
    }
  }
#pragma unroll
  for (int i = 0; i < 32; ++i) {
    const int c = half * 32 + i;
    atomicAdd(&red[c], s[i]);
    atomicAdd(&red[64 + c], q[i]);
  }
  __syncthreads();
  if (tid < 128) atomicAdd(&stats[tid], red[tid]);
}

// ------------------------------------------------------------ finalize ----
__global__ void finalize_kernel(const float* __restrict__ g, const float* __restrict__ be,
                                const float* __restrict__ st, float* __restrict__ sc,
                                float* __restrict__ sh, int C) {
  const int c = threadIdx.x;
  if (c < C) {
    const float mean = st[c] / kM;
    const float var = st[C + c] / kM - mean * mean;
    const float scale = g[c] / sqrtf(var + 1e-5f);
    sc[c] = scale;
    sh[c] = be[c] - mean * scale;
  }
}

// =================== FULL PATH: A (stats1 + y1 store) ======================
__global__ __launch_bounds__(256) void mlpA_kernel(
    const float* __restrict__ x, const float* __restrict__ nxyz,
    const int* __restrict__ idx, const float* __restrict__ U,
    const float* __restrict__ W0, const float* __restrict__ b0,
    const float* __restrict__ W1, const float* __restrict__ b1v,
    const float* __restrict__ scsh, float* __restrict__ stats,
    unsigned short* __restrict__ y1out) {
  __shared__ unsigned short a_lds[128 * kLdsK];
  __shared__ unsigned short w_lds[64 * kLdsK];
  __shared__ float red[128];
  __shared__ float4 w0c[64];
  __shared__ float2 sc0l[64];
  const int tid = threadIdx.x;
  const int p0 = blockIdx.x * 128;
  if (tid < 128) red[tid] = 0.0f;
  if (tid < 64) {
    w0c[tid] = make_float4(W0[tid * kCF + 0], W0[tid * kCF + 1],
                           W0[tid * kCF + 2], b0[tid]);
    sc0l[tid] = make_float2(scsh[tid], scsh[64 + tid]);
  }
  for (int f = tid; f < 64 * 16; f += 256) {  // W1 bf16
    const int d = f >> 4, k4 = (f & 15) * 4;
    const float4 vw = *(const float4*)(W1 + d * 64 + k4);
    unsigned* dst = (unsigned*)(w_lds + d * kLdsK + k4);
    dst[0] = pack2bf(vw.x, vw.y);
    dst[1] = pack2bf(vw.z, vw.w);
  }
  __syncthreads();
  {  // gather + y0 + bn0 + relu -> a_lds (bf16); wave-local rows
    const int pt = tid >> 1, half = tid & 1;
    const int pg = p0 + pt;
    const int v = idx[pg];
    const int b = pg >> 15;
    const int sct = (pg & (kSK - 1)) >> 5;
    const float* xp = x + ((size_t)b * kN + v) * 3;
    const float* np = nxyz + ((size_t)b * kS + sct) * 3;
    const float rx = xp[0] - np[0], ry = xp[1] - np[1], rz = xp[2] - np[2];
    const float4* up = (const float4*)(U + ((size_t)b * kN + v) * 64 + half * 32);
    unsigned* dst = (unsigned*)(a_lds + pt * kLdsK + half * 32);
#pragma unroll
    for (int i = 0; i < 8; ++i) {
      const float4 u4 = up[i];
      const float uu[4] = {u4.x, u4.y, u4.z, u4.w};
      float a1[4];
#pragma unroll
      for (int j = 0; j < 4; ++j) {
        const int c = half * 32 + i * 4 + j;
        const float4 wc = w0c[c];
        const float y = uu[j] + rx * wc.x + ry * wc.y + rz * wc.z + wc.w;
        const float2 ss = sc0l[c];
        a1[j] = fmaxf(fmaf(y, ss.x, ss.y), 0.0f);
      }
      dst[2 * i + 0] = pack2bf(a1[0], a1[1]);
      dst[2 * i + 1] = pack2bf(a1[2], a1[3]);
    }
  }
  __syncthreads();

  const int w = tid >> 6, lane = tid & 63, lr = lane & 15, lk = lane >> 4;
  f32x4 acc1[2][4];
#pragma unroll
  for (int mi = 0; mi < 2; ++mi)
#pragma unroll
    for (int ni = 0; ni < 4; ++ni) acc1[mi][ni] = (f32x4){0.f, 0.f, 0.f, 0.f};
#pragma unroll
  for (int ks = 0; ks < 2; ++ks) {
    const int k = lk * 8 + ks * 32;
    const bf16x8 a0 = *(const bf16x8*)(a_lds + (32 * w + lr) * kLdsK + k);
    const bf16x8 a1 = *(const bf16x8*)(a_lds + (32 * w + 16 + lr) * kLdsK + k);
#pragma unroll
    for (int ni = 0; ni < 4; ++ni) {
      const bf16x8 bv = *(const bf16x8*)(w_lds + (16 * ni + lr) * kLdsK + k);
      acc1[0][ni] = __builtin_amdgcn_mfma_f32_16x16x32_bf16(a0, bv, acc1[0][ni], 0, 0, 0);
      acc1[1][ni] = __builtin_amdgcn_mfma_f32_16x16x32_bf16(a1, bv, acc1[1][ni], 0, 0, 0);
    }
  }
  // stats1 (f32, pre-quantization) + repack y1 = acc1 + b1 as bf16 (wave-local)
#pragma unroll
  for (int ni = 0; ni < 4; ++ni) {
    const int ch = 16 * ni + lr;
    const float bb = b1v[ch];
    float ss = 0.f, qq = 0.f;
#pragma unroll
    for (int mi = 0; mi < 2; ++mi)
#pragma unroll
      for (int r = 0; r < 4; ++r) {
        const float y = acc1[mi][ni][r] + bb;
        ss += y;
        qq += y * y;
        const int row = 32 * w + 16 * mi + lk * 4 + r;
        a_lds[row * kLdsK + ch] = f2bf(y);
      }
    atomicAdd(&red[ch], ss);
    atomicAdd(&red[64 + ch], qq);
  }
  __syncthreads();
  {  // coalesced y1 store (64 B/thread)
    const int row = tid >> 1, hf = tid & 1;
    const uint4* s4 = (const uint4*)(a_lds + row * kLdsK + hf * 32);
    uint4* d4 = (uint4*)(y1out + (size_t)(p0 + row) * 64 + hf * 32);
    d4[0] = s4[0]; d4[1] = s4[1]; d4[2] = s4[2]; d4[3] = s4[3];
  }
  if (tid < 128) atomicAdd(&stats[128 + tid], red[tid]);
}

// ============ FULL PATH: B (stats2 + pre-BN K-pool max/min) ================
__global__ __launch_bounds__(256) void mlpB_kernel(
    const unsigned short* __restrict__ y1in, const float* __restrict__ W2,
    const float* __restrict__ b2v, const float* __restrict__ scsh,
    float* __restrict__ stats, float* __restrict__ pmax,
    float* __restrict__ pmin) {
  __shared__ unsigned short a_lds[128 * kLdsK];
  __shared__ unsigned short w_lds[128 * kLdsK];
  __shared__ float red[256];
  __shared__ float2 s1l[64];
  const int tid = threadIdx.x;
  const int p0 = blockIdx.x * 128;
  red[tid] = 0.0f;
  if (tid < 64) s1l[tid] = make_float2(scsh[128 + tid], scsh[192 + tid]);
  __syncthreads();
  for (int f = tid; f < 128 * 16; f += 256) {  // W2 bf16
    const int d = f >> 4, k4 = (f & 15) * 4;
    const float4 vw = *(const float4*)(W2 + d * 64 + k4);
    unsigned* dst = (unsigned*)(w_lds + d * kLdsK + k4);
    dst[0] = pack2bf(vw.x, vw.y);
    dst[1] = pack2bf(vw.z, vw.w);
  }
  {  // y1 -> bn1 + relu -> a_lds (bf16)
    const int row = tid >> 1, hf = tid & 1;
    const uint4* src = (const uint4*)(y1in + (size_t)(p0 + row) * 64 + hf * 32);
    const uint4 qa = src[0], qb = src[1], qc = src[2], qd = src[3];
    const unsigned in[16] = {qa.x, qa.y, qa.z, qa.w, qb.x, qb.y, qb.z, qb.w,
                             qc.x, qc.y, qc.z, qc.w, qd.x, qd.y, qd.z, qd.w};
    unsigned* dst = (unsigned*)(a_lds + row * kLdsK) + hf * 16;
#pragma unroll
    for (int i2 = 0; i2 < 16; ++i2) {
      const unsigned u = in[i2];
      const int ch0 = hf * 32 + i2 * 2;
      const float2 sA = s1l[ch0];
      const float2 sB = s1l[ch0 + 1];
      const float flo = __uint_as_float(u << 16);
      const float fhi = __uint_as_float(u & 0xffff0000u);
      const float alo = fmaxf(fmaf(flo, sA.x, sA.y), 0.0f);
      const float ahi = fmaxf(fmaf(fhi, sB.x, sB.y), 0.0f);
      dst[i2] = pack2bf(alo, ahi);
    }
  }
  __syncthreads();

  const int w = tid >> 6, lane = tid & 63, lr = lane & 15, lk = lane >> 4;
  f32x4 acc2[2][8];
#pragma unroll
  for (int mi = 0; mi < 2; ++mi)
#pragma unroll
    for (int ni = 0; ni < 8; ++ni) acc2[mi][ni] = (f32x4){0.f, 0.f, 0.f, 0.f};
#pragma unroll
  for (int ks = 0; ks < 2; ++ks) {
    const int k = lk * 8 + ks * 32;
    const bf16x8 a0 = *(const bf16x8*)(a_lds + (32 * w + lr) * kLdsK + k);
    const bf16x8 a1 = *(const bf16x8*)(a_lds + (32 * w + 16 + lr) * kLdsK + k);
#pragma unroll
    for (int ni = 0; ni < 8; ++ni) {
      const bf16x8 bv = *(const bf16x8*)(w_lds + (16 * ni + lr) * kLdsK + k);
      acc2[0][ni] = __builtin_amdgcn_mfma_f32_16x16x32_bf16(a0, bv, acc2[0][ni], 0, 0, 0);
      acc2[1][ni] = __builtin_amdgcn_mfma_f32_16x16x32_bf16(a1, bv, acc2[1][ni], 0, 0, 0);
    }
  }
  // stats2 + per-group pre-BN max/min (wave owns rows [32w, 32w+32))
  float mxv[8], mnv[8];
#pragma unroll
  for (int ni = 0; ni < 8; ++ni) {
    const int ch = 16 * ni + lr;
    const float bb = b2v[ch];
    float ss = 0.f, qq = 0.f;
    float mx = -3.4e38f, mn = 3.4e38f;
#pragma unroll
    for (int mi = 0; mi < 2; ++mi)
#pragma unroll
      for (int r = 0; r < 4; ++r) {
        const float a = acc2[mi][ni][r];
        const float y = a + bb;
        ss += y;
        qq += y * y;
        mx = fmaxf(mx, a);
        mn = fminf(mn, a);
      }
    atomicAdd(&red[ch], ss);
    atomicAdd(&red[128 + ch], qq);
    mx = fmaxf(mx, __shfl_xor(mx, 16, 64));
    mx = fmaxf(mx, __shfl_xor(mx, 32, 64));
    mn = fminf(mn, __shfl_xor(mn, 16, 64));
    mn = fminf(mn, __shfl_xor(mn, 32, 64));
    mxv[ni] = mx + bb;
    mnv[ni] = mn + bb;
  }
  __syncthreads();
  atomicAdd(&stats[256 + tid], red[tid]);
  const int pg0 = p0 + 32 * w;
  const int ob = pg0 >> 15;
  const int os = (pg0 & (kSK - 1)) >> 5;
  if (lane < 16) {
#pragma unroll
    for (int ni = 0; ni < 8; ++ni) {
      const size_t off = ((size_t)ob * 128 + 16 * ni + lane) * kS + os;
      pmax[off] = mxv[ni];
      pmin[off] = mnv[ni];
    }
  }
}

// ============ FULL PATH: C (bn2+relu on pooled values; monotone) ===========
__global__ __launch_bounds__(256) void poolbn_kernel(
    const float* __restrict__ pmax, const float* __restrict__ pmin,
    const float* __restrict__ scsh, float* __restrict__ out) {
  const int gid = blockIdx.x * 256 + threadIdx.x;
  const int c = (gid >> 10) & 127;
  const float sc = scsh[256 + c];
  const float sh = scsh[384 + c];
  const float p = (sc >= 0.f) ? pmax[gid] : pmin[gid];
  out[gid] = fmaxf(fmaf(p, sc, sh), 0.0f);
}

// =================== FALLBACK (ws < full): round-5 mlp path ================
template <int STAGE>
__global__ __launch_bounds__(256) void mlp_kernel(
    const float* __restrict__ x, const float* __restrict__ nxyz,
    const int* __restrict__ idx, const float* __restrict__ U,
    const float* __restrict__ W0, const float* __restrict__ b0,
    const float* __restrict__ W1, const float* __restrict__ b1v,
    const float* __restrict__ W2, const float* __restrict__ b2v,
    const float* __restrict__ scsh, float* __restrict__ stats,
    float* __restrict__ out) {
  __shared__ unsigned short a_lds[128 * kLdsK];
  __shared__ unsigned short w_lds[128 * kLdsK];
  __shared__ float red[256];
  __shared__ float4 w0c[64];
  __shared__ float2 sc0l[64];
  const int tid = threadIdx.x;
  const int p0 = blockIdx.x * 128;
  red[tid] = 0.0f;
  if (tid < 64) {
    w0c[tid] = make_float4(W0[tid * kCF + 0], W0[tid * kCF + 1],
                           W0[tid * kCF + 2], b0[tid]);
    sc0l[tid] = make_float2(scsh[tid], scsh[64 + tid]);
  }
  for (int f = tid; f < 64 * 16; f += 256) {
    const int d = f >> 4, k4 = (f & 15) * 4;
    const float4 vw = *(const float4*)(W1 + d * 64 + k4);
    unsigned* dst = (unsigned*)(w_lds + d * kLdsK + k4);
    dst[0] = pack2bf(vw.x, vw.y);
    dst[1] = pack2bf(vw.z, vw.w);
  }
  __syncthreads();
  {
    const int pt = tid >> 1, half = tid & 1;
    const int pg = p0 + pt;
    const int v = idx[pg];
    const int b = pg >> 15;
    const int sct = (pg & (kSK - 1)) >> 5;
    const float* xp = x + ((size_t)b * kN + v) * 3;
    const float* np = nxyz + ((size_t)b * kS + sct) * 3;
    const float rx = xp[0] - np[0], ry = xp[1] - np[1], rz = xp[2] - np[2];
    const float4* up = (const float4*)(U + ((size_t)b * kN + v) * 64 + half * 32);
    unsigned* dst = (unsigned*)(a_lds + pt * kLdsK + half * 32);
#pragma unroll
    for (int i = 0; i < 8; ++i) {
      const float4 u4 = up[i];
      const float uu[4] = {u4.x, u4.y, u4.z, u4.w};
      float a1[4];
#pragma unroll
      for (int j = 0; j < 4; ++j) {
        const int c = half * 32 + i * 4 + j;
        const float4 wc = w0c[c];
        const float y = uu[j] + rx * wc.x + ry * wc.y + rz * wc.z + wc.w;
        const float2 ss = sc0l[c];
        a1[j] = fmaxf(fmaf(y, ss.x, ss.y), 0.0f);
      }
      dst[2 * i + 0] = pack2bf(a1[0], a1[1]);
      dst[2 * i + 1] = pack2bf(a1[2], a1[3]);
    }
  }
  __syncthreads();

  const int w = tid >> 6, lane = tid & 63, lr = lane & 15, lk = lane >> 4;
  f32x4 acc1[2][4];
#pragma unroll
  for (int mi = 0; mi < 2; ++mi)
#pragma unroll
    for (int ni = 0; ni < 4; ++ni) acc1[mi][ni] = (f32x4){0.f, 0.f, 0.f, 0.f};
#pragma unroll
  for (int ks = 0; ks < 2; ++ks) {
    const int k = lk * 8 + ks * 32;
    const bf16x8 a0 = *(const bf16x8*)(a_lds + (32 * w + lr) * kLdsK + k);
    const bf16x8 a1 = *(const bf16x8*)(a_lds + (32 * w + 16 + lr) * kLdsK + k);
#pragma unroll
    for (int ni = 0; ni < 4; ++ni) {
      const bf16x8 bv = *(const bf16x8*)(w_lds + (16 * ni + lr) * kLdsK + k);
      acc1[0][ni] = __builtin_amdgcn_mfma_f32_16x16x32_bf16(a0, bv, acc1[0][ni], 0, 0, 0);
      acc1[1][ni] = __builtin_amdgcn_mfma_f32_16x16x32_bf16(a1, bv, acc1[1][ni], 0, 0, 0);
    }
  }

  if constexpr (STAGE == 1) {
#pragma unroll
    for (int ni = 0; ni < 4; ++ni) {
      const int ch = 16 * ni + lr;
      const float bb = b1v[ch];
      float ss = 0.f, qq = 0.f;
#pragma unroll
      for (int mi = 0; mi < 2; ++mi)
#pragma unroll
        for (int r = 0; r < 4; ++r) {
          const float y = acc1[mi][ni][r] + bb;
          ss += y;
          qq += y * y;
        }
      atomicAdd(&red[ch], ss);
      atomicAdd(&red[64 + ch], qq);
    }
    __syncthreads();
    if (tid < 128) atomicAdd(&stats[128 + tid], red[tid]);
    return;
  } else {
    __syncthreads();
#pragma unroll
    for (int ni = 0; ni < 4; ++ni) {
      const int ch = 16 * ni + lr;
      const float bb = b1v[ch];
      const float sc1 = scsh[128 + ch], sh1 = scsh[192 + ch];
#pragma unroll
      for (int mi = 0; mi < 2; ++mi)
#pragma unroll
        for (int r = 0; r < 4; ++r) {
          const int row = 32 * w + 16 * mi + lk * 4 + r;
          const float val = fmaxf(fmaf(acc1[mi][ni][r] + bb, sc1, sh1), 0.0f);
          a_lds[row * kLdsK + ch] = f2bf(val);
        }
    }
    for (int f = tid; f < 128 * 16; f += 256) {
      const int d = f >> 4, k4 = (f & 15) * 4;
      const float4 vw = *(const float4*)(W2 + d * 64 + k4);
      unsigned* dst = (unsigned*)(w_lds + d * kLdsK + k4);
      dst[0] = pack2bf(vw.x, vw.y);
      dst[1] = pack2bf(vw.z, vw.w);
    }
    __syncthreads();

    f32x4 acc2[2][8];
#pragma unroll
    for (int mi = 0; mi < 2; ++mi)
#pragma unroll
      for (int ni = 0; ni < 8; ++ni) acc2[mi][ni] = (f32x4){0.f, 0.f, 0.f, 0.f};
#pragma unroll
    for (int ks = 0; ks < 2; ++ks) {
      const int k = lk * 8 + ks * 32;
      const bf16x8 a0 = *(const bf16x8*)(a_lds + (32 * w + lr) * kLdsK + k);
      const bf16x8 a1 = *(const bf16x8*)(a_lds + (32 * w + 16 + lr) * kLdsK + k);
#pragma unroll
      for (int ni = 0; ni < 8; ++ni) {
        const bf16x8 bv = *(const bf16x8*)(w_lds + (16 * ni + lr) * kLdsK + k);
        acc2[0][ni] = __builtin_amdgcn_mfma_f32_16x16x32_bf16(a0, bv, acc2[0][ni], 0, 0, 0);
        acc2[1][ni] = __builtin_amdgcn_mfma_f32_16x16x32_bf16(a1, bv, acc2[1][ni], 0, 0, 0);
      }
    }

    if constexpr (STAGE == 2) {
#pragma unroll
      for (int ni = 0; ni < 8; ++ni) {
        const int ch = 16 * ni + lr;
        const float bb = b2v[ch];
        float ss = 0.f, qq = 0.f;
#pragma unroll
        for (int mi = 0; mi < 2; ++mi)
#pragma unroll
          for (int r = 0; r < 4; ++r) {
            const float y = acc2[mi][ni][r] + bb;
            ss += y;
            qq += y * y;
          }
        atomicAdd(&red[ch], ss);
        atomicAdd(&red[128 + ch], qq);
      }
      __syncthreads();
      atomicAdd(&stats[256 + tid], red[tid]);
    } else {
      float mx[8];
#pragma unroll
      for (int ni = 0; ni < 8; ++ni) {
        const int ch = 16 * ni + lr;
        const float bb = b2v[ch];
        const float sc2 = scsh[256 + ch], sh2 = scsh[384 + ch];
        float m = -1.0f;
#pragma unroll
        for (int mi = 0; mi < 2; ++mi)
#pragma unroll
          for (int r = 0; r < 4; ++r)
            m = fmaxf(m, fmaxf(fmaf(acc2[mi][ni][r] + bb, sc2, sh2), 0.0f));
        mx[ni] = m;
      }
#pragma unroll
      for (int ni = 0; ni < 8; ++ni) {
        mx[ni] = fmaxf(mx[ni], __shfl_xor(mx[ni], 16, 64));
        mx[ni] = fmaxf(mx[ni], __shfl_xor(mx[ni], 32, 64));
      }
      const int pg0 = p0 + 32 * w;
      const int ob = pg0 >> 15;
      const int os = (pg0 & (kSK - 1)) >> 5;
      if (lane < 16) {
#pragma unroll
        for (int ni = 0; ni < 8; ++ni)
          out[((size_t)ob * 128 + 16 * ni + lane) * kS + os] = mx[ni];
      }
    }
  }
}

// --------------------------------------------------------------- launch ----
extern "C" void kernel_launch(void* const* d_in, const int* in_sizes, int n_in,
                              void* d_out, int out_size, void* d_ws, size_t ws_size,
                              hipStream_t stream) {
  const float* x   = (const float*)d_in[0];
  const float* xc  = (const float*)d_in[1];
  const float* W0  = (const float*)d_in[2];
  const float* b0  = (const float*)d_in[3];
  const float* g0  = (const float*)d_in[4];
  const float* be0 = (const float*)d_in[5];
  const float* W1  = (const float*)d_in[6];
  const float* b1  = (const float*)d_in[7];
  const float* g1  = (const float*)d_in[8];
  const float* be1 = (const float*)d_in[9];
  const float* W2  = (const float*)d_in[10];
  const float* b2  = (const float*)d_in[11];
  const float* g2  = (const float*)d_in[12];
  const float* be2 = (const float*)d_in[13];
  float* out = (float*)d_out;
  char* ws = (char*)d_ws;
  float* nxyz  = (float*)(ws);
  int*   idx   = (int*)(ws + kOffIdx);
  float* stats = (float*)(ws + kOffStats);
  float* scsh  = (float*)(ws + kOffScsh);
  float* U     = (float*)(ws + kOffU);
  float* pmax  = (float*)(ws + kOffPmax);
  float* pmin  = (float*)(ws + kOffPmin);
  unsigned short* y1 = (unsigned short*)(ws + kOffY1);
  (void)in_sizes; (void)n_in; (void)out_size;

  hipMemsetAsync(stats, 0, 512 * sizeof(float), stream);
  k1_kernel<<<16 + 512, 256, 0, stream>>>(x, xc, W0, nxyz, U);
  ballq_kernel<<<(kB * kS) / 4, 256, 0, stream>>>(x, nxyz, idx);
  stats0_kernel<<<512, 256, 0, stream>>>(x, nxyz, idx, U, W0, b0, stats);
  finalize_kernel<<<1, 128, 0, stream>>>(g0, be0, stats, scsh, scsh + 64, 64);

  if (ws_size >= kWsNeedF) {
    mlpA_kernel<<<kPT / 128, 256, 0, stream>>>(x, nxyz, idx, U, W0, b0, W1, b1,
                                               scsh, stats, y1);
    finalize_kernel<<<1, 128, 0, stream>>>(g1, be1, stats + 128, scsh + 128, scsh + 192, 64);
    mlpB_kernel<<<kPT / 128, 256, 0, stream>>>(y1, W2, b2, scsh, stats, pmax, pmin);
    finalize_kernel<<<1, 128, 0, stream>>>(g2, be2, stats + 256, scsh + 256, scsh + 384, 128);
    poolbn_kernel<<<(kB * 128 * kS) / 256, 256, 0, stream>>>(pmax, pmin, scsh, out);
  } else {
    mlp_kernel<1><<<kPT / 128, 256, 0, stream>>>(x, nxyz, idx, U, W0, b0, W1, b1,
                                                 W2, b2, scsh, stats, out);
    finalize_kernel<<<1, 128, 0, stream>>>(g1, be1, stats + 128, scsh + 128, scsh + 192, 64);
    mlp_kernel<2><<<kPT / 128, 256, 0, stream>>>(x, nxyz, idx, U, W0, b0, W1, b1,
                                                 W2, b2, scsh, stats, out);
    finalize_kernel<<<1, 128, 0, stream>>>(g2, be2, stats + 256, scsh + 256, scsh + 384, 128);
    mlp_kernel<3><<<kPT / 128, 256, 0, stream>>>(x, nxyz, idx, U, W0, b0, W1, b1,
                                                 W2, b2, scsh, stats, out);
  }
}